// Round 8
// baseline (352.072 us; speedup 1.0000x reference)
//
#include <hip/hip_runtime.h>

// Transformer block on MI355X (gfx950).
// B=2, T=2048, C=1024, H=16, D=64. All GEMMs in bf16 MFMA (16x16x32).
// R5: attention causal pairing. R7/R8: asm ds_read + vmcnt pipelines.
// R11: fc2 XCD remap (FETCH 143->57MB). R12: reg-pipelined frags.
// R13: attn VALU trim. R14: attn XCD remap + fused A/B pair.
// R15: 3-buffer LDS: occupancy unchanged -> occupancy not the limiter.
// R16: R15+bank swizzle: SQ_LDS_BANK_CONFLICT stuck at 2^22 (SATURATED,
//      non-discriminating) and dur flat -> conflicts not the limiter.
// R17: model: per CU-round 96 ds_read_b128 x ~12cy ~= 1150cy LDS-pipe vs
//      78cy matrix/wave -> LDS-READ-PIPE bound at 512B/MFMA. Fix: 256^2
//      block, 8 waves, per-wave 128x64 out -> 12 reads / 32 MFMAs =
//      375B/MFMA (-27%), +33% MFMA per round. 4 LDS buffers (128KB),
//      same depth-3 counted-vmcnt schedule, single frag set (wait12
//      before MFMA; 4-buf rotation keeps read-buf != write-buf).

typedef unsigned short u16;
typedef unsigned int u32;
typedef __attribute__((ext_vector_type(8))) short v8s;   // 8 x bf16 (4 VGPR)
typedef __attribute__((ext_vector_type(4))) float v4f;   // MFMA acc

#define GAS __attribute__((address_space(1)))
#define LAS __attribute__((address_space(3)))

__device__ __forceinline__ u16 f2bf(float f) {
  u32 u = __float_as_uint(f);
  u = (u + 0x7FFF + ((u >> 16) & 1)) >> 16;  // RNE
  return (u16)u;
}
__device__ __forceinline__ u32 f2bf2(float lo, float hi) {
  u32 r;
  asm("v_cvt_pk_bf16_f32 %0, %1, %2" : "=v"(r) : "v"(lo), "v"(hi));
  return r;
}
__device__ __forceinline__ float exp2g(float x) {
  return __builtin_amdgcn_exp2f(x);  // v_exp_f32: native 2^x
}
__device__ __forceinline__ float bf2f(u16 h) {
  return __uint_as_float(((u32)h) << 16);
}
__device__ __forceinline__ float fast_tanh(float x) {
  return 1.f - 2.f / (1.f + __expf(2.f * x));
}

// ---------------- weight transpose + fp32->bf16 convert ----------------
__global__ __launch_bounds__(256)
void wtrans(const float* __restrict__ W, u16* __restrict__ Wt, int K, int N) {
  __shared__ float tile[32][33];
  const int n0 = blockIdx.x << 5, k0 = blockIdx.y << 5;
  const int r = threadIdx.x >> 5, c = threadIdx.x & 31;
#pragma unroll
  for (int i = 0; i < 4; ++i)
    tile[r + 8 * i][c] = W[(size_t)(k0 + r + 8 * i) * N + n0 + c];
  __syncthreads();
#pragma unroll
  for (int i = 0; i < 4; ++i)
    Wt[(size_t)(n0 + r + 8 * i) * K + k0 + c] = f2bf(tile[c][r + 8 * i]);
}

// ---------------- LayerNorm (f32 in -> bf16 out), C=1024 ----------------
__global__ __launch_bounds__(256)
void ln_bf16(const float* __restrict__ x, const float* __restrict__ g,
             const float* __restrict__ be, u16* __restrict__ out) {
  constexpr int C = 1024;
  const int row = blockIdx.x, t = threadIdx.x;
  const float4 v = ((const float4*)(x + (size_t)row * C))[t];
  float s = v.x + v.y + v.z + v.w;
#pragma unroll
  for (int m = 32; m >= 1; m >>= 1) s += __shfl_xor(s, m);
  __shared__ float red[4], red2[4];
  if ((t & 63) == 0) red[t >> 6] = s;
  __syncthreads();
  const float mu = (red[0] + red[1] + red[2] + red[3]) * (1.f / C);
  const float dx = v.x - mu, dy = v.y - mu, dz = v.z - mu, dw = v.w - mu;
  float s2 = dx * dx + dy * dy + dz * dz + dw * dw;
#pragma unroll
  for (int m = 32; m >= 1; m >>= 1) s2 += __shfl_xor(s2, m);
  if ((t & 63) == 0) red2[t >> 6] = s2;
  __syncthreads();
  const float var = (red2[0] + red2[1] + red2[2] + red2[3]) * (1.f / C);
  const float rs = rsqrtf(var + 1e-5f);
  const int c = t << 2;
  uint2 pk;
  pk.x = f2bf2(dx * rs * g[c + 0] + be[c + 0], dy * rs * g[c + 1] + be[c + 1]);
  pk.y = f2bf2(dz * rs * g[c + 2] + be[c + 2], dw * rs * g[c + 3] + be[c + 3]);
  *(uint2*)(out + (size_t)row * C + c) = pk;
}

// ------- GEMM 256x256, 8 waves, per-wave 128x64, depth-3, 4 LDS bufs -----
// 512 threads. Per K-step(32): wave reads 8 A-frags + 4 B-frags (12
// ds_read_b128) -> 32 MFMAs = 375B/MFMA. Staging: 4 global_load_lds/tile.
// Steady vmcnt(8) drains current tile, 2 tiles in flight. Buffer kt&3;
// issue (kt+3)&3 != kt&3; all waves' wait12 precede the barrier after
// which a buffer is rewritten -> no read/write race.
template <int EPI>
__global__ __launch_bounds__(512, 2)
void gemm_bt_p256(const u16* __restrict__ A, const u16* __restrict__ Bt,
                  const float* __restrict__ bias, const float* __restrict__ res,
                  void* __restrict__ outp, int M, int N, int K) {
  __shared__ u16 As[4][256 * 32];
  __shared__ u16 Bs[4][256 * 32];
  const int tid = threadIdx.x;
  const int wave = tid >> 6, lane = tid & 63;
  const int m0 = blockIdx.y << 8, n0 = blockIdx.x << 8;

  v4f acc[8][4];
  const v4f vz = {0.f, 0.f, 0.f, 0.f};
#pragma unroll
  for (int i = 0; i < 8; ++i)
#pragma unroll
    for (int j = 0; j < 4; ++j) acc[i][j] = vz;

  const int wm = (wave >> 2) << 7;     // 0 or 128
  const int wn = (wave & 3) << 6;      // 0,64,128,192
  const int fr = lane & 15;
  const int fg = lane >> 4;

  // staging: thread t covers row t>>2, 16B chunk t&3 (swizzled), rows
  // 0..127 in instr0, 128..255 in instr1.
  const int sr = tid >> 2;
  const int sc = (((tid & 3) ^ ((tid >> 4) & 3)) << 3);  // swizzled src chunk
  const u16* gA0 = A + (size_t)(m0 + sr) * K + sc;
  const u16* gA1 = gA0 + (size_t)128 * K;
  const u16* gB0 = Bt + (size_t)(n0 + sr) * K + sc;
  const u16* gB1 = gB0 + (size_t)128 * K;
  const int aoff = wave * 512;         // u16 elems: wave covers 16 rows (1KB)

  const u32 asb = (u32)(size_t)(LAS const u16*)&As[0][0];
  const u32 bsb = (u32)(size_t)(LAS const u16*)&Bs[0][0];
  const int cgp = fg ^ ((fr >> 2) & 3);  // swizzled read chunk
  const u32 afrag = (u32)(((wm + fr) << 6) + (cgp << 4));  // bytes
  const u32 bfrag = (u32)(((wn + fr) << 6) + (cgp << 4));

  const int nk = K >> 5;  // 32

#define P256_ISSUE(t, bf)                                                         \
  do {                                                                            \
    const int k0_ = (t) << 5;                                                     \
    __builtin_amdgcn_global_load_lds((GAS const u32*)(gA0 + k0_),                 \
                                     (LAS u32*)(As[bf] + aoff), 16, 0, 0);        \
    __builtin_amdgcn_global_load_lds((GAS const u32*)(gA1 + k0_),                 \
                                     (LAS u32*)(As[bf] + aoff + 4096), 16, 0, 0); \
    __builtin_amdgcn_global_load_lds((GAS const u32*)(gB0 + k0_),                 \
                                     (LAS u32*)(Bs[bf] + aoff), 16, 0, 0);        \
    __builtin_amdgcn_global_load_lds((GAS const u32*)(gB1 + k0_),                 \
                                     (LAS u32*)(Bs[bf] + aoff + 4096), 16, 0, 0); \
  } while (0)

  v8s a[8], b[4];
  auto ldfr = [&](int buf) __attribute__((always_inline)) {
    const u32 ab = asb + ((u32)buf << 14) + afrag;  // buf stride 16 KB
    const u32 bb = bsb + ((u32)buf << 14) + bfrag;
    asm volatile("ds_read_b128 %0, %1 offset:0"    : "=v"(a[0]) : "v"(ab));
    asm volatile("ds_read_b128 %0, %1 offset:1024" : "=v"(a[1]) : "v"(ab));
    asm volatile("ds_read_b128 %0, %1 offset:2048" : "=v"(a[2]) : "v"(ab));
    asm volatile("ds_read_b128 %0, %1 offset:3072" : "=v"(a[3]) : "v"(ab));
    asm volatile("ds_read_b128 %0, %1 offset:4096" : "=v"(a[4]) : "v"(ab));
    asm volatile("ds_read_b128 %0, %1 offset:5120" : "=v"(a[5]) : "v"(ab));
    asm volatile("ds_read_b128 %0, %1 offset:6144" : "=v"(a[6]) : "v"(ab));
    asm volatile("ds_read_b128 %0, %1 offset:7168" : "=v"(a[7]) : "v"(ab));
    asm volatile("ds_read_b128 %0, %1 offset:0"    : "=v"(b[0]) : "v"(bb));
    asm volatile("ds_read_b128 %0, %1 offset:1024" : "=v"(b[1]) : "v"(bb));
    asm volatile("ds_read_b128 %0, %1 offset:2048" : "=v"(b[2]) : "v"(bb));
    asm volatile("ds_read_b128 %0, %1 offset:3072" : "=v"(b[3]) : "v"(bb));
    asm volatile("s_waitcnt lgkmcnt(0)"
                 : "+v"(a[0]), "+v"(a[1]), "+v"(a[2]), "+v"(a[3]),
                   "+v"(a[4]), "+v"(a[5]), "+v"(a[6]), "+v"(a[7]),
                   "+v"(b[0]), "+v"(b[1]), "+v"(b[2]), "+v"(b[3])
                 :
                 : "memory");
  };
  auto mfma32 = [&]() __attribute__((always_inline)) {
#pragma unroll
    for (int i = 0; i < 8; ++i)
#pragma unroll
      for (int j = 0; j < 4; ++j)
        acc[i][j] = __builtin_amdgcn_mfma_f32_16x16x32_bf16(a[i], b[j], acc[i][j], 0, 0, 0);
  };

  P256_ISSUE(0, 0);
  P256_ISSUE(1, 1);
  P256_ISSUE(2, 2);

  for (int kt = 0; kt < nk - 3; ++kt) {
    asm volatile("s_waitcnt vmcnt(8)" ::: "memory");  // tile kt resident
    __builtin_amdgcn_s_barrier();
    P256_ISSUE(kt + 3, (kt + 3) & 3);
    __builtin_amdgcn_sched_barrier(0);  // gloads ahead of ds_reads
    ldfr(kt & 3);
    mfma32();
  }
  asm volatile("s_waitcnt vmcnt(8)" ::: "memory");
  __builtin_amdgcn_s_barrier();
  ldfr((nk - 3) & 3);
  mfma32();
  asm volatile("s_waitcnt vmcnt(4)" ::: "memory");
  __builtin_amdgcn_s_barrier();
  ldfr((nk - 2) & 3);
  mfma32();
  asm volatile("s_waitcnt vmcnt(0)" ::: "memory");
  __builtin_amdgcn_s_barrier();
  ldfr((nk - 1) & 3);
  mfma32();
#undef P256_ISSUE

  const int er = (lane >> 4) << 2;
#pragma unroll
  for (int mi = 0; mi < 8; ++mi) {
#pragma unroll
    for (int ni = 0; ni < 4; ++ni) {
      const int col = n0 + wn + ni * 16 + fr;
      const float bcol = bias[col];
#pragma unroll
      for (int r = 0; r < 4; ++r) {
        const int row = m0 + wm + mi * 16 + er + r;
        float v = acc[mi][ni][r] + bcol;
        if constexpr (EPI == 1) {
          const float t = fast_tanh(0.7978845608028654f * (v + 0.044715f * v * v * v));
          v = 0.5f * v * (1.f + t);
        }
        if constexpr (EPI == 2) {
          v += res[(size_t)row * N + col];
          ((float*)outp)[(size_t)row * N + col] = v;
        } else {
          ((u16*)outp)[(size_t)row * N + col] = f2bf(v);
        }
      }
    }
  }
}

// ------- GEMM 128x128, depth-3, 3 LDS buffers (fc2 w/ REMAP) -------------
template <int EPI, int REMAP>
__global__ __launch_bounds__(256)
void gemm_bt_p(const u16* __restrict__ A, const u16* __restrict__ Bt,
               const float* __restrict__ bias, const float* __restrict__ res,
               void* __restrict__ outp, int M, int N, int K) {
  __shared__ u16 As[3][128 * 32];
  __shared__ u16 Bs[3][128 * 32];
  const int tid = threadIdx.x;
  const int wave = tid >> 6, lane = tid & 63;
  int bx, by;
  if constexpr (REMAP) {
    const int wg = blockIdx.y * (int)gridDim.x + blockIdx.x;
    const int xcd = wg & 7;
    const int seq = wg >> 3;
    bx = seq & 7;
    by = ((seq >> 3) << 3) + xcd;
  } else {
    bx = blockIdx.x;
    by = blockIdx.y;
  }
  const int m0 = by << 7, n0 = bx << 7;

  v4f acc[4][4];
  const v4f vz = {0.f, 0.f, 0.f, 0.f};
#pragma unroll
  for (int i = 0; i < 4; ++i)
#pragma unroll
    for (int j = 0; j < 4; ++j) acc[i][j] = vz;

  const int wm = (wave >> 1) << 6, wn = (wave & 1) << 6;
  const int sr = lane >> 2;
  const int sc = (((lane & 3) ^ ((lane >> 4) & 3)) << 3);
  const int fr = lane & 15;
  const int fg = lane >> 4;
  const int c0 = wave << 1;

  const u16* gA0 = A + (size_t)(m0 + c0 * 16 + sr) * K + sc;
  const u16* gA1 = A + (size_t)(m0 + c0 * 16 + 16 + sr) * K + sc;
  const u16* gB0 = Bt + (size_t)(n0 + c0 * 16 + sr) * K + sc;
  const u16* gB1 = Bt + (size_t)(n0 + c0 * 16 + 16 + sr) * K + sc;
  const int aoff = c0 * 512;  // elements within a buffer

  const u32 asb = (u32)(size_t)(LAS const u16*)&As[0][0];
  const u32 bsb = (u32)(size_t)(LAS const u16*)&Bs[0][0];
  const int cgp = fg ^ ((fr >> 2) & 3);
  const u32 afrag = (u32)(((wm + fr) << 6) + (cgp << 4));  // bytes
  const u32 bfrag = (u32)(((wn + fr) << 6) + (cgp << 4));

  const int nk = K >> 5;  // even, >= 4

#define P128_ISSUE(t, bf)                                                        \
  do {                                                                           \
    const int k0_ = (t) << 5;                                                    \
    __builtin_amdgcn_global_load_lds((GAS const u32*)(gA0 + k0_),                \
                                     (LAS u32*)(As[bf] + aoff), 16, 0, 0);       \
    __builtin_amdgcn_global_load_lds((GAS const u32*)(gA1 + k0_),                \
                                     (LAS u32*)(As[bf] + aoff + 512), 16, 0, 0); \
    __builtin_amdgcn_global_load_lds((GAS const u32*)(gB0 + k0_),                \
                                     (LAS u32*)(Bs[bf] + aoff), 16, 0, 0);       \
    __builtin_amdgcn_global_load_lds((GAS const u32*)(gB1 + k0_),                \
                                     (LAS u32*)(Bs[bf] + aoff + 512), 16, 0, 0); \
  } while (0)

  auto ldfr = [&](int buf, v8s (&a)[4], v8s (&b)[4]) __attribute__((always_inline)) {
    const u32 ab = asb + ((u32)buf << 13) + afrag;  // buf stride 8 KB
    const u32 bb = bsb + ((u32)buf << 13) + bfrag;
    asm volatile("ds_read_b128 %0, %1 offset:0"    : "=v"(a[0]) : "v"(ab));
    asm volatile("ds_read_b128 %0, %1 offset:1024" : "=v"(a[1]) : "v"(ab));
    asm volatile("ds_read_b128 %0, %1 offset:2048" : "=v"(a[2]) : "v"(ab));
    asm volatile("ds_read_b128 %0, %1 offset:3072" : "=v"(a[3]) : "v"(ab));
    asm volatile("ds_read_b128 %0, %1 offset:0"    : "=v"(b[0]) : "v"(bb));
    asm volatile("ds_read_b128 %0, %1 offset:1024" : "=v"(b[1]) : "v"(bb));
    asm volatile("ds_read_b128 %0, %1 offset:2048" : "=v"(b[2]) : "v"(bb));
    asm volatile("ds_read_b128 %0, %1 offset:3072" : "=v"(b[3]) : "v"(bb));
  };
  auto wait8 = [&](v8s (&a)[4], v8s (&b)[4]) __attribute__((always_inline)) {
    asm volatile("s_waitcnt lgkmcnt(0)"
                 : "+v"(a[0]), "+v"(a[1]), "+v"(a[2]), "+v"(a[3]),
                   "+v"(b[0]), "+v"(b[1]), "+v"(b[2]), "+v"(b[3])
                 :
                 : "memory");
  };
  auto mfma16 = [&](v8s (&a)[4], v8s (&b)[4]) __attribute__((always_inline)) {
#pragma unroll
    for (int i = 0; i < 4; ++i)
#pragma unroll
      for (int j = 0; j < 4; ++j)
        acc[i][j] = __builtin_amdgcn_mfma_f32_16x16x32_bf16(a[i], b[j], acc[i][j], 0, 0, 0);
  };

  v8s aX[4], bX[4], aY[4], bY[4];

  P128_ISSUE(0, 0);
  P128_ISSUE(1, 1);
  P128_ISSUE(2, 2);
  asm volatile("s_waitcnt vmcnt(8)" ::: "memory");  // tile 0 resident
  __builtin_amdgcn_s_barrier();
  ldfr(0, aX, bX);
  wait8(aX, bX);

  int br = 1, bi = 0;
  for (int kt = 0; kt < nk - 2; kt += 2) {
    asm volatile("s_waitcnt vmcnt(4)" ::: "memory");  // tile kt+1 resident
    __builtin_amdgcn_s_barrier();
    ldfr(br, aY, bY);
    if (kt + 3 < nk) P128_ISSUE(kt + 3, bi);
    __builtin_amdgcn_sched_barrier(0);
    mfma16(aX, bX);
    wait8(aY, bY);
    br = (br == 2) ? 0 : br + 1;
    bi = (bi == 2) ? 0 : bi + 1;
    asm volatile("s_waitcnt vmcnt(4)" ::: "memory");
    __builtin_amdgcn_s_barrier();
    ldfr(br, aX, bX);
    if (kt + 4 < nk) P128_ISSUE(kt + 4, bi);
    __builtin_amdgcn_sched_barrier(0);
    mfma16(aY, bY);
    wait8(aX, bX);
    br = (br == 2) ? 0 : br + 1;
    bi = (bi == 2) ? 0 : bi + 1;
  }
  asm volatile("s_waitcnt vmcnt(0)" ::: "memory");
  __builtin_amdgcn_s_barrier();
  ldfr(br, aY, bY);
  __builtin_amdgcn_sched_barrier(0);
  mfma16(aX, bX);
  wait8(aY, bY);
  mfma16(aY, bY);
#undef P128_ISSUE

  const int er = (lane >> 4) << 2;
#pragma unroll
  for (int mi = 0; mi < 4; ++mi) {
#pragma unroll
    for (int ni = 0; ni < 4; ++ni) {
      const int col = n0 + wn + ni * 16 + fr;
      const float bcol = bias[col];
#pragma unroll
      for (int r = 0; r < 4; ++r) {
        const int row = m0 + wm + mi * 16 + er + r;
        float v = acc[mi][ni][r] + bcol;
        if constexpr (EPI == 1) {
          const float t = fast_tanh(0.7978845608028654f * (v + 0.044715f * v * v * v));
          v = 0.5f * v * (1.f + t);
        }
        if constexpr (EPI == 2) {
          v += res[(size_t)row * N + col];
          ((float*)outp)[(size_t)row * N + col] = v;
        } else {
          ((u16*)outp)[(size_t)row * N + col] = f2bf(v);
        }
      }
    }
  }
}

// ------- GEMM 128x64, depth-3 prefetch, asm ds_read, swizzled (proj) -----
template <int EPI>
__global__ __launch_bounds__(256)
void gemm_bt_n64(const u16* __restrict__ A, const u16* __restrict__ Bt,
                 const float* __restrict__ bias, const float* __restrict__ res,
                 void* __restrict__ outp, int M, int N, int K) {
  __shared__ u16 As[4][128 * 32];
  __shared__ u16 Bs[4][64 * 32];
  const int tid = threadIdx.x;
  const int wave = tid >> 6, lane = tid & 63;
  const int m0 = blockIdx.y << 7, n0 = blockIdx.x << 6;

  v4f acc[4][2];
  const v4f vz = {0.f, 0.f, 0.f, 0.f};
#pragma unroll
  for (int i = 0; i < 4; ++i)
#pragma unroll
    for (int j = 0; j < 2; ++j) acc[i][j] = vz;

  const int wm = (wave >> 1) << 6, wn = (wave & 1) << 5;
  const int sr = lane >> 2;
  const int sc = (((lane & 3) ^ ((lane >> 4) & 3)) << 3);  // R16 swizzle
  const int fr = lane & 15;
  const int fg = lane >> 4;

  const u16* gA0 = A + (size_t)(m0 + wave * 32 + sr) * K + sc;
  const u16* gA1 = A + (size_t)(m0 + wave * 32 + 16 + sr) * K + sc;
  const u16* gB0 = Bt + (size_t)(n0 + wave * 16 + sr) * K + sc;
  const int aoff = wave * 1024;
  const int boff = wave * 512;

  const u32 asb = (u32)(size_t)(LAS const u16*)&As[0][0];
  const u32 bsb = (u32)(size_t)(LAS const u16*)&Bs[0][0];
  const int cgp = fg ^ ((fr >> 2) & 3);
  const u32 afrag = (u32)(((wm + fr) << 6) + (cgp << 4));
  const u32 bfrag = (u32)(((wn + fr) << 6) + (cgp << 4));

  const int nk = K >> 5;

#define N64_ISSUE(t, bf)                                                      \
  do {                                                                        \
    const int k0_ = (t) << 5;                                                 \
    __builtin_amdgcn_global_load_lds((GAS const u32*)(gA0 + k0_),             \
                                     (LAS u32*)(As[bf] + aoff), 16, 0, 0);    \
    __builtin_amdgcn_global_load_lds((GAS const u32*)(gA1 + k0_),             \
                                     (LAS u32*)(As[bf] + aoff + 512), 16, 0, 0); \
    __builtin_amdgcn_global_load_lds((GAS const u32*)(gB0 + k0_),             \
                                     (LAS u32*)(Bs[bf] + boff), 16, 0, 0);    \
  } while (0)

  N64_ISSUE(0, 0);
  N64_ISSUE(1, 1);
  N64_ISSUE(2, 2);

  auto compute = [&](int kt) __attribute__((always_inline)) {
    const u32 ab = asb + ((u32)(kt & 3) << 13) + afrag;  // A buf stride 8 KB
    const u32 bb = bsb + ((u32)(kt & 3) << 12) + bfrag;  // B buf stride 4 KB
    v8s a0, a1, a2, a3, b0, b1;
    asm volatile("ds_read_b128 %0, %1 offset:0"    : "=v"(a0) : "v"(ab));
    asm volatile("ds_read_b128 %0, %1 offset:1024" : "=v"(a1) : "v"(ab));
    asm volatile("ds_read_b128 %0, %1 offset:2048" : "=v"(a2) : "v"(ab));
    asm volatile("ds_read_b128 %0, %1 offset:3072" : "=v"(a3) : "v"(ab));
    asm volatile("ds_read_b128 %0, %1 offset:0"    : "=v"(b0) : "v"(bb));
    asm volatile("ds_read_b128 %0, %1 offset:1024" : "=v"(b1) : "v"(bb));
    asm volatile("s_waitcnt lgkmcnt(0)"
                 : "+v"(a0), "+v"(a1), "+v"(a2), "+v"(a3), "+v"(b0), "+v"(b1)
                 :
                 : "memory");
    acc[0][0] = __builtin_amdgcn_mfma_f32_16x16x32_bf16(a0, b0, acc[0][0], 0, 0, 0);
    acc[0][1] = __builtin_amdgcn_mfma_f32_16x16x32_bf16(a0, b1, acc[0][1], 0, 0, 0);
    acc[1][0] = __builtin_amdgcn_mfma_f32_16x16x32_bf16(a1, b0, acc[1][0], 0, 0, 0);
    acc[1][1] = __builtin_amdgcn_mfma_f32_16x16x32_bf16(a1, b1, acc[1][1], 0, 0, 0);
    acc[2][0] = __builtin_amdgcn_mfma_f32_16x16x32_bf16(a2, b0, acc[2][0], 0, 0, 0);
    acc[2][1] = __builtin_amdgcn_mfma_f32_16x16x32_bf16(a2, b1, acc[2][1], 0, 0, 0);
    acc[3][0] = __builtin_amdgcn_mfma_f32_16x16x32_bf16(a3, b0, acc[3][0], 0, 0, 0);
    acc[3][1] = __builtin_amdgcn_mfma_f32_16x16x32_bf16(a3, b1, acc[3][1], 0, 0, 0);
  };

  for (int kt = 0; kt < nk - 2; ++kt) {
    asm volatile("s_waitcnt vmcnt(6)" ::: "memory");
    __builtin_amdgcn_s_barrier();
    if (kt + 3 < nk) N64_ISSUE(kt + 3, (kt + 3) & 3);
    compute(kt);
  }
  asm volatile("s_waitcnt vmcnt(3)" ::: "memory");
  __builtin_amdgcn_s_barrier();
  compute(nk - 2);
  asm volatile("s_waitcnt vmcnt(0)" ::: "memory");
  __builtin_amdgcn_s_barrier();
  compute(nk - 1);
#undef N64_ISSUE

  const int er = (lane >> 4) << 2;
#pragma unroll
  for (int mi = 0; mi < 4; ++mi) {
#pragma unroll
    for (int ni = 0; ni < 2; ++ni) {
      const int col = n0 + wn + ni * 16 + fr;
      const float bcol = bias[col];
#pragma unroll
      for (int r = 0; r < 4; ++r) {
        const int row = m0 + wm + mi * 16 + er + r;
        float v = acc[mi][ni][r] + bcol;
        if constexpr (EPI == 1) {
          const float t = fast_tanh(0.7978845608028654f * (v + 0.044715f * v * v * v));
          v = 0.5f * v * (1.f + t);
        }
        if constexpr (EPI == 2) {
          v += res[(size_t)row * N + col];
          ((float*)outp)[(size_t)row * N + col] = v;
        } else {
          ((u16*)outp)[(size_t)row * N + col] = f2bf(v);
        }
      }
    }
  }
}

// ---------------- V -> Vt [B,H,D,T] bf16 (transpose via LDS) -------------
__global__ __launch_bounds__(256)
void transpose_v(const u16* __restrict__ qkv, u16* __restrict__ Vt) {
  __shared__ u16 tile[64][65];
  const int t0 = blockIdx.x << 6;
  const int bh = blockIdx.y;
  const int b = bh >> 4, h = bh & 15;
  const int r4 = threadIdx.x >> 6, c = threadIdx.x & 63;
#pragma unroll
  for (int i = 0; i < 16; ++i) {
    const int r = r4 * 16 + i;
    tile[r][c] = qkv[(size_t)(b * 2048 + t0 + r) * 3072 + 2048 + h * 64 + c];
  }
  __syncthreads();
#pragma unroll
  for (int i = 0; i < 16; ++i) {
    const int d = r4 * 16 + i;
    Vt[(size_t)bh * 64 * 2048 + (size_t)d * 2048 + t0 + c] = tile[c][d];
  }
}

// ---------------- flash attention (causal, balanced pairing) -------------
constexpr int PSTR = 88;  // P row stride (u16): 176B = 16B-mult, 2-way banks
constexpr float ATT_SC = 0.18033688011112042f;  // (1/8) * log2(e)

template <bool MASKED>
__device__ __forceinline__ void soft16(
    const v4f (&st)[4], float (&e)[4][4], v4f (&ot)[4],
    float& m_i, float& l_i, const int kb, const int qrow,
    const int fr, const int fg) {
  const int q = qrow + fr;
#pragma unroll
  for (int ks = 0; ks < 4; ++ks) {
    const v4f sv = st[ks] * ATT_SC;
#pragma unroll
    for (int r = 0; r < 4; ++r) {
      float v = sv[r];
      if (MASKED) v = (kb + ks * 16 + fg * 4 + r <= q) ? v : -1e30f;
      e[ks][r] = v;
    }
  }
  float mk0 = fmaxf(fmaxf(e[0][0], e[0][1]), fmaxf(e[0][2], e[0][3]));
  float mk1 = fmaxf(fmaxf(e[1][0], e[1][1]), fmaxf(e[1][2], e[1][3]));
  float mk2 = fmaxf(fmaxf(e[2][0], e[2][1]), fmaxf(e[2][2], e[2][3]));
  float mk3 = fmaxf(fmaxf(e[3][0], e[3][1]), fmaxf(e[3][2], e[3][3]));
  float mt = fmaxf(fmaxf(mk0, mk1), fmaxf(mk2, mk3));
  mt = fmaxf(mt, __shfl_xor(mt, 16));
  mt = fmaxf(mt, __shfl_xor(mt, 32));
  if (__any(mt > m_i)) {  // EXACT: alpha==1 when false
    const float m_new = fmaxf(m_i, mt);
    const float alpha = exp2g(m_i - m_new);
    m_i = m_new;
    l_i *= alpha;
#pragma unroll
    for (int ds = 0; ds < 4; ++ds) ot[ds] *= alpha;
  }
#pragma unroll
  for (int ks = 0; ks < 4; ++ks)
#pragma unroll
    for (int r = 0; r < 4; ++r) e[ks][r] = exp2g(e[ks][r] - m_i);
  float s0 = (e[0][0] + e[0][1]) + (e[0][2] + e[0][3]);
  float s1 = (e[1][0] + e[1][1]) + (e[1][2] + e[1][3]);
  float s2 = (e[2][0] + e[2][1]) + (e[2][2] + e[2][3]);
  float s3 = (e[3][0] + e[3][1]) + (e[3][2] + e[3][3]);
  float ls = (s0 + s1) + (s2 + s3);
  ls += __shfl_xor(ls, 16);
  ls += __shfl_xor(ls, 32);
  l_i += ls;
}

__device__ __forceinline__ void pstore(const float (&e)[4][4],
                                       u16* __restrict__ pw,
                                       const int fr, const int fg) {
#pragma unroll
  for (int ks = 0; ks < 4; ++ks) {
    uint2 pk;
    pk.x = f2bf2(e[ks][0], e[ks][1]);
    pk.y = f2bf2(e[ks][2], e[ks][3]);
    *(uint2*)&pw[fr * PSTR + ks * 16 + fg * 4] = pk;
  }
}

__device__ __forceinline__ void pvacc(const v8s (&vfr)[4][2],
                                      const u16* __restrict__ pw,
                                      v4f (&ot)[4], const int fr, const int fg) {
  const v8s pf0 = *(const v8s*)&pw[fr * PSTR + fg * 8];
  const v8s pf1 = *(const v8s*)&pw[fr * PSTR + 32 + fg * 8];
  __builtin_amdgcn_s_setprio(1);
#pragma unroll
  for (int ds = 0; ds < 4; ++ds) {
    ot[ds] = __builtin_amdgcn_mfma_f32_16x16x32_bf16(vfr[ds][0], pf0, ot[ds], 0, 0, 0);
    ot[ds] = __builtin_amdgcn_mfma_f32_16x16x32_bf16(vfr[ds][1], pf1, ot[ds], 0, 0, 0);
  }
  __builtin_amdgcn_s_setprio(0);
}

template <bool MASKED>
__device__ __forceinline__ void attn_sub(
    const v8s (&kf)[4][2], const v8s (&vfr)[4][2], const v8s (&qf)[2],
    v4f (&ot)[4], float& m_i, float& l_i, u16* __restrict__ pw,
    const int kb, const int qrow, const int fr, const int fg) {
  const v4f vz = {0.f, 0.f, 0.f, 0.f};
  v4f st[4];
  __builtin_amdgcn_s_setprio(1);
#pragma unroll
  for (int ks = 0; ks < 4; ++ks) {
    st[ks] = vz;
    st[ks] = __builtin_amdgcn_mfma_f32_16x16x32_bf16(kf[ks][0], qf[0], st[ks], 0, 0, 0);
    st[ks] = __builtin_amdgcn_mfma_f32_16x16x32_bf16(kf[ks][1], qf[1], st[ks], 0, 0, 0);
  }
  __builtin_amdgcn_s_setprio(0);
  float e[4][4];
  soft16<MASKED>(st, e, ot, m_i, l_i, kb, qrow, fr, fg);
  pstore(e, pw, fr, fg);
  pvacc(vfr, pw, ot, fr, fg);
}

template <bool MASKA>
__device__ __forceinline__ void attn_sub_pair(
    const v8s (&kf)[4][2], const v8s (&vfr)[4][2],
    const v8s (&qfA)[2], const v8s (&qfB)[2],
    v4f (&otA)[4], v4f (&otB)[4],
    float& mA, float& lA, float& mB, float& lB,
    u16* __restrict__ pwA, u16* __restrict__ pwB,
    const int kb, const int rowA, const int rowB, const int fr, const int fg) {
  const v4f vz = {0.f, 0.f, 0.f, 0.f};
  v4f stA[4], stB[4];
  __builtin_amdgcn_s_setprio(1);
#pragma unroll
  for (int ks = 0; ks < 4; ++ks) {
    stA[ks] = vz;
    stA[ks] = __builtin_amdgcn_mfma_f32_16x16x32_bf16(kf[ks][0], qfA[0], stA[ks], 0, 0, 0);
    stA[ks] = __builtin_amdgcn_mfma_f32_16x16x32_bf16(kf[ks][1], qfA[1], stA[ks], 0, 0, 0);
  }
#pragma unroll
  for (int ks = 0; ks < 4; ++ks) {
    stB[ks] = vz;
    stB[ks] = __builtin_amdgcn_mfma_f32_16x16x32_bf16(kf[ks][0], qfB[0], stB[ks], 0, 0, 0);
    stB[ks] = __builtin_amdgcn_mfma_f32_16x16x32_bf16(kf[ks][1], qfB[1], stB[ks], 0, 0, 0);
  }
  __builtin_amdgcn_s_setprio(0);
  float eA[4][4];
  soft16<MASKA>(stA, eA, otA, mA, lA, kb, rowA, fr, fg);
  pstore(eA, pwA, fr, fg);
  float eB[4][4];
  soft16<false>(stB, eB, otB, mB, lB, kb, rowB, fr, fg);
  pvacc(vfr, pwA, otA, fr, fg);
  pstore(eB, pwB, fr, fg);
  pvacc(vfr, pwB, otB, fr, fg);
}

__global__ __launch_bounds__(256)
void attn_kernel(const u16* __restrict__ qkv, const u16* __restrict__ Vt,
                 u16* __restrict__ y) {
  constexpr int T = 2048, D = 64, C = 1024, QS = 3072;
  __shared__ alignas(16) u16 Ktile[2][64 * 64];
  __shared__ alignas(16) u16 Vtile[2][64 * 64];
  __shared__ alignas(16) u16 Pw[8][16 * PSTR];

  const int tid = threadIdx.x, wave = tid >> 6, lane = tid & 63;
  const int fr = lane & 15, fg = lane >> 4;
  const int wg = blockIdx.y * 16 + blockIdx.x;
  const int xcd = wg & 7, seq = wg >> 3;
  const int bh = ((seq & 3) << 3) + xcd;
  const int ta = seq >> 2, tb = 31 - ta;
  const int b = bh >> 4, h = bh & 15;
  const u16* qkvb = qkv + (size_t)b * T * QS + h * 64;  // Q base
  const u16* Kg = qkvb + 1024;                          // K base
  const u16* Vh = Vt + (size_t)bh * D * T;
  u16* pwA = &Pw[wave][0];
  u16* pwB = &Pw[4 + wave][0];

  const int rowA = ta * 64 + wave * 16;
  const int rowB = tb * 64 + wave * 16;

  v8s qfA[2], qfB[2];
#pragma unroll
  for (int dh = 0; dh < 2; ++dh) {
    qfA[dh] = *(const v8s*)&qkvb[(size_t)(rowA + fr) * QS + dh * 32 + fg * 8];
    qfB[dh] = *(const v8s*)&qkvb[(size_t)(rowB + fr) * QS + dh * 32 + fg * 8];
  }

  const v4f vz = {0.f, 0.f, 0.f, 0.f};
  v4f otA[4], otB[4];
#pragma unroll
  for (int ds = 0; ds < 4; ++ds) { otA[ds] = vz; otB[ds] = vz; }
  float mA = -1e30f, lA = 0.f, mB = -1e30f, lB = 0.f;

  const int srow = lane >> 3;
  const int sg0 = lane & 7;

  const int nt = tb + 1;
  {
#pragma unroll
    for (int cc = 0; cc < 2; ++cc) {
      const int r0 = wave * 16 + cc * 8;
      const int rr = r0 + srow;
      const int gg = sg0 ^ (rr & 7);
      __builtin_amdgcn_global_load_lds(
          (GAS const u32*)(Kg + (size_t)rr * QS + gg * 8),
          (LAS u32*)(Ktile[0] + r0 * 64), 16, 0, 0);
      __builtin_amdgcn_global_load_lds(
          (GAS const u32*)(Vh + (size_t)rr * T + gg * 8),
          (LAS u32*)(Vtile[0] + r0 * 64), 16, 0, 0);
    }
  }
  for (int kt = 0; kt < nt; ++kt) {
    __syncthreads();
    if (kt + 1 < nt) {
      const int kb1 = (kt + 1) << 6;
      const int nb = (kt + 1) & 1;
#pragma unroll
      for (int cc = 0; cc < 2; ++cc) {
        const int r0 = wave * 16 + cc * 8;
        const int rr = r0 + srow;
        const int gg = sg0 ^ (rr & 7);
        __builtin_amdgcn_global_load_lds(
            (GAS const u32*)(Kg + (size_t)(kb1 + rr) * QS + gg * 8),
            (LAS u32*)(Ktile[nb] + r0 * 64), 16, 0, 0);
        __builtin_amdgcn_global_load_lds(
            (GAS const u32*)(Vh + (size_t)rr * T + kb1 + gg * 8),
            (LAS u32*)(Vtile[nb] + r0 * 64), 16, 0, 0);
      }
    }
    const u16* Kt = Ktile[kt & 1];
    const u16* Vi = Vtile[kt & 1];
    const int kb = kt << 6;
    const int swz = fr & 7;
    v8s kf[4][2], vfr[4][2];
#pragma unroll
    for (int ks = 0; ks < 4; ++ks) {
      const int rr = ks * 16 + fr;
      kf[ks][0] = *(const v8s*)&Kt[rr * 64 + ((0 + fg) ^ swz) * 8];
      kf[ks][1] = *(const v8s*)&Kt[rr * 64 + ((4 + fg) ^ swz) * 8];
      vfr[ks][0] = *(const v8s*)&Vi[rr * 64 + ((0 + fg) ^ swz) * 8];
      vfr[ks][1] = *(const v8s*)&Vi[rr * 64 + ((4 + fg) ^ swz) * 8];
    }
    if (kt < ta) {
      attn_sub_pair<false>(kf, vfr, qfA, qfB, otA, otB, mA, lA, mB, lB,
                           pwA, pwB, kb, rowA, rowB, fr, fg);
    } else if (kt == ta) {
      attn_sub_pair<true>(kf, vfr, qfA, qfB, otA, otB, mA, lA, mB, lB,
                          pwA, pwB, kb, rowA, rowB, fr, fg);
    } else if (kt < tb) {
      attn_sub<false>(kf, vfr, qfB, otB, mB, lB, pwB, kb, rowB, fr, fg);
    } else {
      attn_sub<true>(kf, vfr, qfB, otB, mB, lB, pwB, kb, rowB, fr, fg);
    }
  }

  const float invA = 1.f / lA, invB = 1.f / lB;
#pragma unroll
  for (int ds = 0; ds < 4; ++ds) {
    uint2 pa, pb;
    pa.x = f2bf2(otA[ds][0] * invA, otA[ds][1] * invA);
    pa.y = f2bf2(otA[ds][2] * invA, otA[ds][3] * invA);
    pb.x = f2bf2(otB[ds][0] * invB, otB[ds][1] * invB);
    pb.y = f2bf2(otB[ds][2] * invB, otB[ds][3] * invB);
    *(uint2*)&y[(size_t)(b * T + rowA + fr) * C + h * D + ds * 16 + fg * 4] = pa;
    *(uint2*)&y[(size_t)(b * T + rowB + fr) * C + h * D + ds * 16 + fg * 4] = pb;
  }
}

// ------------------------------- launch ----------------------------------
extern "C" void kernel_launch(void* const* d_in, const int* in_sizes, int n_in,
                              void* d_out, int out_size, void* d_ws, size_t ws_size,
                              hipStream_t stream) {
  const float* x      = (const float*)d_in[0];
  const float* ln1_g  = (const float*)d_in[1];
  const float* ln1_b  = (const float*)d_in[2];
  const float* W_attn = (const float*)d_in[3];
  const float* b_attn = (const float*)d_in[4];
  const float* W_o    = (const float*)d_in[5];
  const float* b_o    = (const float*)d_in[6];
  const float* ln2_g  = (const float*)d_in[7];
  const float* ln2_b  = (const float*)d_in[8];
  const float* W_fc   = (const float*)d_in[9];
  const float* b_fc   = (const float*)d_in[10];
  const float* W_fc2  = (const float*)d_in[11];
  const float* b_fc2  = (const float*)d_in[12];
  float* out = (float*)d_out;
  char* ws = (char*)d_ws;

  const size_t MB = 1u << 20;
  u16* Wattn_t = (u16*)(ws + 0 * MB);   // 6MB
  u16* Wo_t    = (u16*)(ws + 6 * MB);   // 2MB
  u16* Wfc_t   = (u16*)(ws + 8 * MB);   // 8MB
  u16* Wfc2_t  = (u16*)(ws + 16 * MB);  // 8MB
  float* x1    = (float*)(ws + 24 * MB); // 16MB
  u16* h1      = (u16*)(ws + 40 * MB);  // 8MB
  u16* qkv     = (u16*)(ws + 48 * MB);  // 24MB (alive through attn)
  u16* Vt      = (u16*)(ws + 88 * MB);  // 8MB
  u16* yb      = (u16*)(ws + 40 * MB);  // reuse h1 (dead after qkv GEMM)
  u16* h2      = (u16*)(ws + 48 * MB);  // reuse qkv (dead after attn)
  u16* ab      = (u16*)(ws + 56 * MB);  // 32MB (56..88)

  wtrans<<<dim3(3072 / 32, 1024 / 32), 256, 0, stream>>>(W_attn, Wattn_t, 1024, 3072);
  wtrans<<<dim3(1024 / 32, 1024 / 32), 256, 0, stream>>>(W_o, Wo_t, 1024, 1024);
  wtrans<<<dim3(4096 / 32, 1024 / 32), 256, 0, stream>>>(W_fc, Wfc_t, 1024, 4096);
  wtrans<<<dim3(1024 / 32, 4096 / 32), 256, 0, stream>>>(W_fc2, Wfc2_t, 4096, 1024);

  ln_bf16<<<4096, 256, 0, stream>>>(x, ln1_g, ln1_b, h1);
  gemm_bt_p256<0><<<dim3(3072 / 256, 4096 / 256), 512, 0, stream>>>(
      h1, Wattn_t, b_attn, nullptr, qkv, 4096, 3072, 1024);
  transpose_v<<<dim3(2048 / 64, 32), 256, 0, stream>>>(qkv, Vt);
  attn_kernel<<<dim3(16, 32), 256, 0, stream>>>(qkv, Vt, yb);
  gemm_bt_n64<2><<<dim3(1024 / 64, 4096 / 128), 256, 0, stream>>>(
      yb, Wo_t, b_o, x, x1, 4096, 1024, 1024);
  ln_bf16<<<4096, 256, 0, stream>>>(x1, ln2_g, ln2_b, h2);
  gemm_bt_p256<1><<<dim3(4096 / 256, 4096 / 256), 512, 0, stream>>>(
      h2, Wfc_t, b_fc, nullptr, ab, 4096, 4096, 1024);
  gemm_bt_p<2, 1><<<dim3(1024 / 128, 4096 / 128), 256, 0, stream>>>(
      ab, Wfc2_t, b_fc2, x1, out, 4096, 1024, 4096);
}

// Round 9
// 343.319 us; speedup vs baseline: 1.0255x; 1.0255x over previous
//
#include <hip/hip_runtime.h>

// Transformer block on MI355X (gfx950).
// B=2, T=2048, C=1024, H=16, D=64. All GEMMs in bf16 MFMA (16x16x32).
// R5: attention causal pairing. R7/R8: asm ds_read + vmcnt pipelines.
// R11: fc2 XCD remap (FETCH 143->57MB ideal). R12: reg-pipelined frags.
// R13: attn VALU trim. R14: attn XCD remap + fused A/B pair.
// R15/R16: 3-buffer LDS + bank swizzle (both ~neutral; conflict counter
//      saturates at 2^22, non-discriminating).
// R17: 256^2 tile REGRESSED (61 vs 58us): 128KB LDS -> 1 block/CU, qkv
//      grid 192 blocks -> 25% CUs idle. Reverted.
// R18: generalize R11's XCD remap to ALL gemm_bt_p uses (qkv, fc1, fc2):
//      xcd=wg&7, q=wg>>3, bx=q%gx, by=xcd+8*(q/gx). fc1 FETCH is 41MB vs
//      16.8 ideal (A-panels demand-fetched on 8 XCDs); colocating the
//      x-blocks of each A-panel on one XCD makes staging L2-resident.

typedef unsigned short u16;
typedef unsigned int u32;
typedef __attribute__((ext_vector_type(8))) short v8s;   // 8 x bf16 (4 VGPR)
typedef __attribute__((ext_vector_type(4))) float v4f;   // MFMA acc

#define GAS __attribute__((address_space(1)))
#define LAS __attribute__((address_space(3)))

__device__ __forceinline__ u16 f2bf(float f) {
  u32 u = __float_as_uint(f);
  u = (u + 0x7FFF + ((u >> 16) & 1)) >> 16;  // RNE
  return (u16)u;
}
__device__ __forceinline__ u32 f2bf2(float lo, float hi) {
  u32 r;
  asm("v_cvt_pk_bf16_f32 %0, %1, %2" : "=v"(r) : "v"(lo), "v"(hi));
  return r;
}
__device__ __forceinline__ float exp2g(float x) {
  return __builtin_amdgcn_exp2f(x);  // v_exp_f32: native 2^x
}
__device__ __forceinline__ float bf2f(u16 h) {
  return __uint_as_float(((u32)h) << 16);
}
__device__ __forceinline__ float fast_tanh(float x) {
  return 1.f - 2.f / (1.f + __expf(2.f * x));
}

// ---------------- weight transpose + fp32->bf16 convert ----------------
__global__ __launch_bounds__(256)
void wtrans(const float* __restrict__ W, u16* __restrict__ Wt, int K, int N) {
  __shared__ float tile[32][33];
  const int n0 = blockIdx.x << 5, k0 = blockIdx.y << 5;
  const int r = threadIdx.x >> 5, c = threadIdx.x & 31;
#pragma unroll
  for (int i = 0; i < 4; ++i)
    tile[r + 8 * i][c] = W[(size_t)(k0 + r + 8 * i) * N + n0 + c];
  __syncthreads();
#pragma unroll
  for (int i = 0; i < 4; ++i)
    Wt[(size_t)(n0 + r + 8 * i) * K + k0 + c] = f2bf(tile[c][r + 8 * i]);
}

// ---------------- LayerNorm (f32 in -> bf16 out), C=1024 ----------------
__global__ __launch_bounds__(256)
void ln_bf16(const float* __restrict__ x, const float* __restrict__ g,
             const float* __restrict__ be, u16* __restrict__ out) {
  constexpr int C = 1024;
  const int row = blockIdx.x, t = threadIdx.x;
  const float4 v = ((const float4*)(x + (size_t)row * C))[t];
  float s = v.x + v.y + v.z + v.w;
#pragma unroll
  for (int m = 32; m >= 1; m >>= 1) s += __shfl_xor(s, m);
  __shared__ float red[4], red2[4];
  if ((t & 63) == 0) red[t >> 6] = s;
  __syncthreads();
  const float mu = (red[0] + red[1] + red[2] + red[3]) * (1.f / C);
  const float dx = v.x - mu, dy = v.y - mu, dz = v.z - mu, dw = v.w - mu;
  float s2 = dx * dx + dy * dy + dz * dz + dw * dw;
#pragma unroll
  for (int m = 32; m >= 1; m >>= 1) s2 += __shfl_xor(s2, m);
  if ((t & 63) == 0) red2[t >> 6] = s2;
  __syncthreads();
  const float var = (red2[0] + red2[1] + red2[2] + red2[3]) * (1.f / C);
  const float rs = rsqrtf(var + 1e-5f);
  const int c = t << 2;
  uint2 pk;
  pk.x = f2bf2(dx * rs * g[c + 0] + be[c + 0], dy * rs * g[c + 1] + be[c + 1]);
  pk.y = f2bf2(dz * rs * g[c + 2] + be[c + 2], dw * rs * g[c + 3] + be[c + 3]);
  *(uint2*)(out + (size_t)row * C + c) = pk;
}

// ------- GEMM 128x128, depth-3, 3 LDS buffers, reg-pipelined, swizzled ---
// REMAP=1: XCD-aware tile remap, generic (requires gridDim.y % 8 == 0):
// xcd = wg&7 (dispatch round-robin), q = wg>>3; bx = q % gx;
// by = xcd + 8*(q/gx). All x-blocks of an A-panel share wg%8 -> one XCD.
template <int EPI, int REMAP>
__global__ __launch_bounds__(256)
void gemm_bt_p(const u16* __restrict__ A, const u16* __restrict__ Bt,
               const float* __restrict__ bias, const float* __restrict__ res,
               void* __restrict__ outp, int M, int N, int K) {
  __shared__ u16 As[3][128 * 32];
  __shared__ u16 Bs[3][128 * 32];
  const int tid = threadIdx.x;
  const int wave = tid >> 6, lane = tid & 63;
  int bx, by;
  if constexpr (REMAP) {
    const int gx = (int)gridDim.x;
    const int wg = blockIdx.y * gx + blockIdx.x;
    const int xcd = wg & 7;
    const int q = wg >> 3;
    bx = q % gx;
    by = xcd + ((q / gx) << 3);
  } else {
    bx = blockIdx.x;
    by = blockIdx.y;
  }
  const int m0 = by << 7, n0 = bx << 7;

  v4f acc[4][4];
  const v4f vz = {0.f, 0.f, 0.f, 0.f};
#pragma unroll
  for (int i = 0; i < 4; ++i)
#pragma unroll
    for (int j = 0; j < 4; ++j) acc[i][j] = vz;

  const int wm = (wave >> 1) << 6, wn = (wave & 1) << 6;
  const int sr = lane >> 2;
  // R16: stager lane's physical chunk is (lane&3); it must FETCH logical
  // chunk (lane&3) ^ ((row>>2)&3) -> same 64B row, coalescing preserved.
  const int sc = (((lane & 3) ^ ((lane >> 4) & 3)) << 3);
  const int fr = lane & 15;
  const int fg = lane >> 4;        // logical chunk of the frag read
  const int c0 = wave << 1;

  const u16* gA0 = A + (size_t)(m0 + c0 * 16 + sr) * K + sc;
  const u16* gA1 = A + (size_t)(m0 + c0 * 16 + 16 + sr) * K + sc;
  const u16* gB0 = Bt + (size_t)(n0 + c0 * 16 + sr) * K + sc;
  const u16* gB1 = Bt + (size_t)(n0 + c0 * 16 + 16 + sr) * K + sc;
  const int aoff = c0 * 512;  // elements within a buffer

  const u32 asb = (u32)(size_t)(LAS const u16*)&As[0][0];
  const u32 bsb = (u32)(size_t)(LAS const u16*)&Bs[0][0];
  // R16: physical chunk = fg ^ ((fr>>2)&3); invariant under row+16 (the
  // offset:1024 immediates), wm/wn multiples of 64 don't affect bits 2-3.
  const int cgp = fg ^ ((fr >> 2) & 3);
  const u32 afrag = (u32)(((wm + fr) << 6) + (cgp << 4));  // bytes
  const u32 bfrag = (u32)(((wn + fr) << 6) + (cgp << 4));

  const int nk = K >> 5;  // even, >= 4

#define P128_ISSUE(t, bf)                                                        \
  do {                                                                           \
    const int k0_ = (t) << 5;                                                    \
    __builtin_amdgcn_global_load_lds((GAS const u32*)(gA0 + k0_),                \
                                     (LAS u32*)(As[bf] + aoff), 16, 0, 0);       \
    __builtin_amdgcn_global_load_lds((GAS const u32*)(gA1 + k0_),                \
                                     (LAS u32*)(As[bf] + aoff + 512), 16, 0, 0); \
    __builtin_amdgcn_global_load_lds((GAS const u32*)(gB0 + k0_),                \
                                     (LAS u32*)(Bs[bf] + aoff), 16, 0, 0);       \
    __builtin_amdgcn_global_load_lds((GAS const u32*)(gB1 + k0_),                \
                                     (LAS u32*)(Bs[bf] + aoff + 512), 16, 0, 0); \
  } while (0)

  // issue 8 ds_read_b128 for LDS buffer `buf` into (a[],b[]) -- no wait
  auto ldfr = [&](int buf, v8s (&a)[4], v8s (&b)[4]) __attribute__((always_inline)) {
    const u32 ab = asb + ((u32)buf << 13) + afrag;  // buf stride 8 KB
    const u32 bb = bsb + ((u32)buf << 13) + bfrag;
    asm volatile("ds_read_b128 %0, %1 offset:0"    : "=v"(a[0]) : "v"(ab));
    asm volatile("ds_read_b128 %0, %1 offset:1024" : "=v"(a[1]) : "v"(ab));
    asm volatile("ds_read_b128 %0, %1 offset:2048" : "=v"(a[2]) : "v"(ab));
    asm volatile("ds_read_b128 %0, %1 offset:3072" : "=v"(a[3]) : "v"(ab));
    asm volatile("ds_read_b128 %0, %1 offset:0"    : "=v"(b[0]) : "v"(bb));
    asm volatile("ds_read_b128 %0, %1 offset:1024" : "=v"(b[1]) : "v"(bb));
    asm volatile("ds_read_b128 %0, %1 offset:2048" : "=v"(b[2]) : "v"(bb));
    asm volatile("ds_read_b128 %0, %1 offset:3072" : "=v"(b[3]) : "v"(bb));
  };
  auto wait8 = [&](v8s (&a)[4], v8s (&b)[4]) __attribute__((always_inline)) {
    asm volatile("s_waitcnt lgkmcnt(0)"
                 : "+v"(a[0]), "+v"(a[1]), "+v"(a[2]), "+v"(a[3]),
                   "+v"(b[0]), "+v"(b[1]), "+v"(b[2]), "+v"(b[3])
                 :
                 : "memory");
  };
  auto mfma16 = [&](v8s (&a)[4], v8s (&b)[4]) __attribute__((always_inline)) {
#pragma unroll
    for (int i = 0; i < 4; ++i)
#pragma unroll
      for (int j = 0; j < 4; ++j)
        acc[i][j] = __builtin_amdgcn_mfma_f32_16x16x32_bf16(a[i], b[j], acc[i][j], 0, 0, 0);
  };

  v8s aX[4], bX[4], aY[4], bY[4];

  P128_ISSUE(0, 0);
  P128_ISSUE(1, 1);
  P128_ISSUE(2, 2);
  asm volatile("s_waitcnt vmcnt(8)" ::: "memory");  // tile 0 resident
  __builtin_amdgcn_s_barrier();
  ldfr(0, aX, bX);
  wait8(aX, bX);

  // buffer rotation: at step k, ldfr reads buf (k+1)%3, issue writes
  // buf k%3 (tile k+3 into tile k's slot -- free after last step's wait8
  // + this step's barrier).
  int br = 1, bi = 0;
  for (int kt = 0; kt < nk - 2; kt += 2) {
    // step kt: mfma on X, frags(kt+1) -> Y
    asm volatile("s_waitcnt vmcnt(4)" ::: "memory");  // tile kt+1 resident
    __builtin_amdgcn_s_barrier();
    ldfr(br, aY, bY);
    if (kt + 3 < nk) P128_ISSUE(kt + 3, bi);
    __builtin_amdgcn_sched_barrier(0);  // keep issues ahead of MFMAs
    mfma16(aX, bX);
    wait8(aY, bY);
    br = (br == 2) ? 0 : br + 1;
    bi = (bi == 2) ? 0 : bi + 1;
    // step kt+1: mfma on Y, frags(kt+2) -> X
    asm volatile("s_waitcnt vmcnt(4)" ::: "memory");
    __builtin_amdgcn_s_barrier();
    ldfr(br, aX, bX);
    if (kt + 4 < nk) P128_ISSUE(kt + 4, bi);
    __builtin_amdgcn_sched_barrier(0);
    mfma16(aY, bY);
    wait8(aX, bX);
    br = (br == 2) ? 0 : br + 1;
    bi = (bi == 2) ? 0 : bi + 1;
  }
  // kt = nk-2: last tile nk-1
  asm volatile("s_waitcnt vmcnt(0)" ::: "memory");
  __builtin_amdgcn_s_barrier();
  ldfr(br, aY, bY);
  __builtin_amdgcn_sched_barrier(0);
  mfma16(aX, bX);
  wait8(aY, bY);
  mfma16(aY, bY);
#undef P128_ISSUE

  const int er = (lane >> 4) << 2;
#pragma unroll
  for (int mi = 0; mi < 4; ++mi) {
#pragma unroll
    for (int ni = 0; ni < 4; ++ni) {
      const int col = n0 + wn + ni * 16 + fr;
      const float bcol = bias[col];
#pragma unroll
      for (int r = 0; r < 4; ++r) {
        const int row = m0 + wm + mi * 16 + er + r;
        float v = acc[mi][ni][r] + bcol;
        if constexpr (EPI == 1) {
          const float t = fast_tanh(0.7978845608028654f * (v + 0.044715f * v * v * v));
          v = 0.5f * v * (1.f + t);
        }
        if constexpr (EPI == 2) {
          v += res[(size_t)row * N + col];
          ((float*)outp)[(size_t)row * N + col] = v;
        } else {
          ((u16*)outp)[(size_t)row * N + col] = f2bf(v);
        }
      }
    }
  }
}

// ------- GEMM 128x64, depth-3 prefetch, asm ds_read, swizzled (proj) -----
template <int EPI>
__global__ __launch_bounds__(256)
void gemm_bt_n64(const u16* __restrict__ A, const u16* __restrict__ Bt,
                 const float* __restrict__ bias, const float* __restrict__ res,
                 void* __restrict__ outp, int M, int N, int K) {
  __shared__ u16 As[4][128 * 32];
  __shared__ u16 Bs[4][64 * 32];
  const int tid = threadIdx.x;
  const int wave = tid >> 6, lane = tid & 63;
  const int m0 = blockIdx.y << 7, n0 = blockIdx.x << 6;

  v4f acc[4][2];
  const v4f vz = {0.f, 0.f, 0.f, 0.f};
#pragma unroll
  for (int i = 0; i < 4; ++i)
#pragma unroll
    for (int j = 0; j < 2; ++j) acc[i][j] = vz;

  const int wm = (wave >> 1) << 6, wn = (wave & 1) << 5;
  const int sr = lane >> 2;
  const int sc = (((lane & 3) ^ ((lane >> 4) & 3)) << 3);  // R16 swizzle
  const int fr = lane & 15;
  const int fg = lane >> 4;

  const u16* gA0 = A + (size_t)(m0 + wave * 32 + sr) * K + sc;
  const u16* gA1 = A + (size_t)(m0 + wave * 32 + 16 + sr) * K + sc;
  const u16* gB0 = Bt + (size_t)(n0 + wave * 16 + sr) * K + sc;
  const int aoff = wave * 1024;
  const int boff = wave * 512;

  const u32 asb = (u32)(size_t)(LAS const u16*)&As[0][0];
  const u32 bsb = (u32)(size_t)(LAS const u16*)&Bs[0][0];
  const int cgp = fg ^ ((fr >> 2) & 3);
  const u32 afrag = (u32)(((wm + fr) << 6) + (cgp << 4));
  const u32 bfrag = (u32)(((wn + fr) << 6) + (cgp << 4));

  const int nk = K >> 5;

#define N64_ISSUE(t, bf)                                                      \
  do {                                                                        \
    const int k0_ = (t) << 5;                                                 \
    __builtin_amdgcn_global_load_lds((GAS const u32*)(gA0 + k0_),             \
                                     (LAS u32*)(As[bf] + aoff), 16, 0, 0);    \
    __builtin_amdgcn_global_load_lds((GAS const u32*)(gA1 + k0_),             \
                                     (LAS u32*)(As[bf] + aoff + 512), 16, 0, 0); \
    __builtin_amdgcn_global_load_lds((GAS const u32*)(gB0 + k0_),             \
                                     (LAS u32*)(Bs[bf] + boff), 16, 0, 0);    \
  } while (0)

  N64_ISSUE(0, 0);
  N64_ISSUE(1, 1);
  N64_ISSUE(2, 2);

  auto compute = [&](int kt) __attribute__((always_inline)) {
    const u32 ab = asb + ((u32)(kt & 3) << 13) + afrag;  // A buf stride 8 KB
    const u32 bb = bsb + ((u32)(kt & 3) << 12) + bfrag;  // B buf stride 4 KB
    v8s a0, a1, a2, a3, b0, b1;
    asm volatile("ds_read_b128 %0, %1 offset:0"    : "=v"(a0) : "v"(ab));
    asm volatile("ds_read_b128 %0, %1 offset:1024" : "=v"(a1) : "v"(ab));
    asm volatile("ds_read_b128 %0, %1 offset:2048" : "=v"(a2) : "v"(ab));
    asm volatile("ds_read_b128 %0, %1 offset:3072" : "=v"(a3) : "v"(ab));
    asm volatile("ds_read_b128 %0, %1 offset:0"    : "=v"(b0) : "v"(bb));
    asm volatile("ds_read_b128 %0, %1 offset:1024" : "=v"(b1) : "v"(bb));
    asm volatile("s_waitcnt lgkmcnt(0)"
                 : "+v"(a0), "+v"(a1), "+v"(a2), "+v"(a3), "+v"(b0), "+v"(b1)
                 :
                 : "memory");
    acc[0][0] = __builtin_amdgcn_mfma_f32_16x16x32_bf16(a0, b0, acc[0][0], 0, 0, 0);
    acc[0][1] = __builtin_amdgcn_mfma_f32_16x16x32_bf16(a0, b1, acc[0][1], 0, 0, 0);
    acc[1][0] = __builtin_amdgcn_mfma_f32_16x16x32_bf16(a1, b0, acc[1][0], 0, 0, 0);
    acc[1][1] = __builtin_amdgcn_mfma_f32_16x16x32_bf16(a1, b1, acc[1][1], 0, 0, 0);
    acc[2][0] = __builtin_amdgcn_mfma_f32_16x16x32_bf16(a2, b0, acc[2][0], 0, 0, 0);
    acc[2][1] = __builtin_amdgcn_mfma_f32_16x16x32_bf16(a2, b1, acc[2][1], 0, 0, 0);
    acc[3][0] = __builtin_amdgcn_mfma_f32_16x16x32_bf16(a3, b0, acc[3][0], 0, 0, 0);
    acc[3][1] = __builtin_amdgcn_mfma_f32_16x16x32_bf16(a3, b1, acc[3][1], 0, 0, 0);
  };

  for (int kt = 0; kt < nk - 2; ++kt) {
    asm volatile("s_waitcnt vmcnt(6)" ::: "memory");
    __builtin_amdgcn_s_barrier();
    if (kt + 3 < nk) N64_ISSUE(kt + 3, (kt + 3) & 3);
    compute(kt);
  }
  asm volatile("s_waitcnt vmcnt(3)" ::: "memory");
  __builtin_amdgcn_s_barrier();
  compute(nk - 2);
  asm volatile("s_waitcnt vmcnt(0)" ::: "memory");
  __builtin_amdgcn_s_barrier();
  compute(nk - 1);
#undef N64_ISSUE

  const int er = (lane >> 4) << 2;
#pragma unroll
  for (int mi = 0; mi < 4; ++mi) {
#pragma unroll
    for (int ni = 0; ni < 2; ++ni) {
      const int col = n0 + wn + ni * 16 + fr;
      const float bcol = bias[col];
#pragma unroll
      for (int r = 0; r < 4; ++r) {
        const int row = m0 + wm + mi * 16 + er + r;
        float v = acc[mi][ni][r] + bcol;
        if constexpr (EPI == 1) {
          const float t = fast_tanh(0.7978845608028654f * (v + 0.044715f * v * v * v));
          v = 0.5f * v * (1.f + t);
        }
        if constexpr (EPI == 2) {
          v += res[(size_t)row * N + col];
          ((float*)outp)[(size_t)row * N + col] = v;
        } else {
          ((u16*)outp)[(size_t)row * N + col] = f2bf(v);
        }
      }
    }
  }
}

// ---------------- V -> Vt [B,H,D,T] bf16 (transpose via LDS) -------------
__global__ __launch_bounds__(256)
void transpose_v(const u16* __restrict__ qkv, u16* __restrict__ Vt) {
  __shared__ u16 tile[64][65];
  const int t0 = blockIdx.x << 6;
  const int bh = blockIdx.y;
  const int b = bh >> 4, h = bh & 15;
  const int r4 = threadIdx.x >> 6, c = threadIdx.x & 63;
#pragma unroll
  for (int i = 0; i < 16; ++i) {
    const int r = r4 * 16 + i;
    tile[r][c] = qkv[(size_t)(b * 2048 + t0 + r) * 3072 + 2048 + h * 64 + c];
  }
  __syncthreads();
#pragma unroll
  for (int i = 0; i < 16; ++i) {
    const int d = r4 * 16 + i;
    Vt[(size_t)bh * 64 * 2048 + (size_t)d * 2048 + t0 + c] = tile[c][d];
  }
}

// ---------------- flash attention (causal, balanced pairing) -------------
constexpr int PSTR = 88;  // P row stride (u16): 176B = 16B-mult, 2-way banks
constexpr float ATT_SC = 0.18033688011112042f;  // (1/8) * log2(e)

template <bool MASKED>
__device__ __forceinline__ void soft16(
    const v4f (&st)[4], float (&e)[4][4], v4f (&ot)[4],
    float& m_i, float& l_i, const int kb, const int qrow,
    const int fr, const int fg) {
  const int q = qrow + fr;
#pragma unroll
  for (int ks = 0; ks < 4; ++ks) {
    const v4f sv = st[ks] * ATT_SC;
#pragma unroll
    for (int r = 0; r < 4; ++r) {
      float v = sv[r];
      if (MASKED) v = (kb + ks * 16 + fg * 4 + r <= q) ? v : -1e30f;
      e[ks][r] = v;
    }
  }
  float mk0 = fmaxf(fmaxf(e[0][0], e[0][1]), fmaxf(e[0][2], e[0][3]));
  float mk1 = fmaxf(fmaxf(e[1][0], e[1][1]), fmaxf(e[1][2], e[1][3]));
  float mk2 = fmaxf(fmaxf(e[2][0], e[2][1]), fmaxf(e[2][2], e[2][3]));
  float mk3 = fmaxf(fmaxf(e[3][0], e[3][1]), fmaxf(e[3][2], e[3][3]));
  float mt = fmaxf(fmaxf(mk0, mk1), fmaxf(mk2, mk3));
  mt = fmaxf(mt, __shfl_xor(mt, 16));
  mt = fmaxf(mt, __shfl_xor(mt, 32));
  if (__any(mt > m_i)) {  // EXACT: alpha==1 when false
    const float m_new = fmaxf(m_i, mt);
    const float alpha = exp2g(m_i - m_new);
    m_i = m_new;
    l_i *= alpha;
#pragma unroll
    for (int ds = 0; ds < 4; ++ds) ot[ds] *= alpha;
  }
#pragma unroll
  for (int ks = 0; ks < 4; ++ks)
#pragma unroll
    for (int r = 0; r < 4; ++r) e[ks][r] = exp2g(e[ks][r] - m_i);
  float s0 = (e[0][0] + e[0][1]) + (e[0][2] + e[0][3]);
  float s1 = (e[1][0] + e[1][1]) + (e[1][2] + e[1][3]);
  float s2 = (e[2][0] + e[2][1]) + (e[2][2] + e[2][3]);
  float s3 = (e[3][0] + e[3][1]) + (e[3][2] + e[3][3]);
  float ls = (s0 + s1) + (s2 + s3);
  ls += __shfl_xor(ls, 16);
  ls += __shfl_xor(ls, 32);
  l_i += ls;
}

__device__ __forceinline__ void pstore(const float (&e)[4][4],
                                       u16* __restrict__ pw,
                                       const int fr, const int fg) {
#pragma unroll
  for (int ks = 0; ks < 4; ++ks) {
    uint2 pk;
    pk.x = f2bf2(e[ks][0], e[ks][1]);
    pk.y = f2bf2(e[ks][2], e[ks][3]);
    *(uint2*)&pw[fr * PSTR + ks * 16 + fg * 4] = pk;
  }
}

__device__ __forceinline__ void pvacc(const v8s (&vfr)[4][2],
                                      const u16* __restrict__ pw,
                                      v4f (&ot)[4], const int fr, const int fg) {
  const v8s pf0 = *(const v8s*)&pw[fr * PSTR + fg * 8];
  const v8s pf1 = *(const v8s*)&pw[fr * PSTR + 32 + fg * 8];
  __builtin_amdgcn_s_setprio(1);
#pragma unroll
  for (int ds = 0; ds < 4; ++ds) {
    ot[ds] = __builtin_amdgcn_mfma_f32_16x16x32_bf16(vfr[ds][0], pf0, ot[ds], 0, 0, 0);
    ot[ds] = __builtin_amdgcn_mfma_f32_16x16x32_bf16(vfr[ds][1], pf1, ot[ds], 0, 0, 0);
  }
  __builtin_amdgcn_s_setprio(0);
}

template <bool MASKED>
__device__ __forceinline__ void attn_sub(
    const v8s (&kf)[4][2], const v8s (&vfr)[4][2], const v8s (&qf)[2],
    v4f (&ot)[4], float& m_i, float& l_i, u16* __restrict__ pw,
    const int kb, const int qrow, const int fr, const int fg) {
  const v4f vz = {0.f, 0.f, 0.f, 0.f};
  v4f st[4];
  __builtin_amdgcn_s_setprio(1);
#pragma unroll
  for (int ks = 0; ks < 4; ++ks) {
    st[ks] = vz;
    st[ks] = __builtin_amdgcn_mfma_f32_16x16x32_bf16(kf[ks][0], qf[0], st[ks], 0, 0, 0);
    st[ks] = __builtin_amdgcn_mfma_f32_16x16x32_bf16(kf[ks][1], qf[1], st[ks], 0, 0, 0);
  }
  __builtin_amdgcn_s_setprio(0);
  float e[4][4];
  soft16<MASKED>(st, e, ot, m_i, l_i, kb, qrow, fr, fg);
  pstore(e, pw, fr, fg);
  pvacc(vfr, pw, ot, fr, fg);
}

template <bool MASKA>
__device__ __forceinline__ void attn_sub_pair(
    const v8s (&kf)[4][2], const v8s (&vfr)[4][2],
    const v8s (&qfA)[2], const v8s (&qfB)[2],
    v4f (&otA)[4], v4f (&otB)[4],
    float& mA, float& lA, float& mB, float& lB,
    u16* __restrict__ pwA, u16* __restrict__ pwB,
    const int kb, const int rowA, const int rowB, const int fr, const int fg) {
  const v4f vz = {0.f, 0.f, 0.f, 0.f};
  v4f stA[4], stB[4];
  __builtin_amdgcn_s_setprio(1);
#pragma unroll
  for (int ks = 0; ks < 4; ++ks) {
    stA[ks] = vz;
    stA[ks] = __builtin_amdgcn_mfma_f32_16x16x32_bf16(kf[ks][0], qfA[0], stA[ks], 0, 0, 0);
    stA[ks] = __builtin_amdgcn_mfma_f32_16x16x32_bf16(kf[ks][1], qfA[1], stA[ks], 0, 0, 0);
  }
#pragma unroll
  for (int ks = 0; ks < 4; ++ks) {
    stB[ks] = vz;
    stB[ks] = __builtin_amdgcn_mfma_f32_16x16x32_bf16(kf[ks][0], qfB[0], stB[ks], 0, 0, 0);
    stB[ks] = __builtin_amdgcn_mfma_f32_16x16x32_bf16(kf[ks][1], qfB[1], stB[ks], 0, 0, 0);
  }
  __builtin_amdgcn_s_setprio(0);
  float eA[4][4];
  soft16<MASKA>(stA, eA, otA, mA, lA, kb, rowA, fr, fg);
  pstore(eA, pwA, fr, fg);
  float eB[4][4];
  soft16<false>(stB, eB, otB, mB, lB, kb, rowB, fr, fg);
  pvacc(vfr, pwA, otA, fr, fg);
  pstore(eB, pwB, fr, fg);
  pvacc(vfr, pwB, otB, fr, fg);
}

__global__ __launch_bounds__(256)
void attn_kernel(const u16* __restrict__ qkv, const u16* __restrict__ Vt,
                 u16* __restrict__ y) {
  constexpr int T = 2048, D = 64, C = 1024, QS = 3072;
  __shared__ alignas(16) u16 Ktile[2][64 * 64];
  __shared__ alignas(16) u16 Vtile[2][64 * 64];
  __shared__ alignas(16) u16 Pw[8][16 * PSTR];

  const int tid = threadIdx.x, wave = tid >> 6, lane = tid & 63;
  const int fr = lane & 15, fg = lane >> 4;
  const int wg = blockIdx.y * 16 + blockIdx.x;
  const int xcd = wg & 7, seq = wg >> 3;
  const int bh = ((seq & 3) << 3) + xcd;
  const int ta = seq >> 2, tb = 31 - ta;
  const int b = bh >> 4, h = bh & 15;
  const u16* qkvb = qkv + (size_t)b * T * QS + h * 64;  // Q base
  const u16* Kg = qkvb + 1024;                          // K base
  const u16* Vh = Vt + (size_t)bh * D * T;
  u16* pwA = &Pw[wave][0];
  u16* pwB = &Pw[4 + wave][0];

  const int rowA = ta * 64 + wave * 16;
  const int rowB = tb * 64 + wave * 16;

  v8s qfA[2], qfB[2];
#pragma unroll
  for (int dh = 0; dh < 2; ++dh) {
    qfA[dh] = *(const v8s*)&qkvb[(size_t)(rowA + fr) * QS + dh * 32 + fg * 8];
    qfB[dh] = *(const v8s*)&qkvb[(size_t)(rowB + fr) * QS + dh * 32 + fg * 8];
  }

  const v4f vz = {0.f, 0.f, 0.f, 0.f};
  v4f otA[4], otB[4];
#pragma unroll
  for (int ds = 0; ds < 4; ++ds) { otA[ds] = vz; otB[ds] = vz; }
  float mA = -1e30f, lA = 0.f, mB = -1e30f, lB = 0.f;

  const int srow = lane >> 3;
  const int sg0 = lane & 7;

  const int nt = tb + 1;
  {
#pragma unroll
    for (int cc = 0; cc < 2; ++cc) {
      const int r0 = wave * 16 + cc * 8;
      const int rr = r0 + srow;
      const int gg = sg0 ^ (rr & 7);
      __builtin_amdgcn_global_load_lds(
          (GAS const u32*)(Kg + (size_t)rr * QS + gg * 8),
          (LAS u32*)(Ktile[0] + r0 * 64), 16, 0, 0);
      __builtin_amdgcn_global_load_lds(
          (GAS const u32*)(Vh + (size_t)rr * T + gg * 8),
          (LAS u32*)(Vtile[0] + r0 * 64), 16, 0, 0);
    }
  }
  for (int kt = 0; kt < nt; ++kt) {
    __syncthreads();
    if (kt + 1 < nt) {
      const int kb1 = (kt + 1) << 6;
      const int nb = (kt + 1) & 1;
#pragma unroll
      for (int cc = 0; cc < 2; ++cc) {
        const int r0 = wave * 16 + cc * 8;
        const int rr = r0 + srow;
        const int gg = sg0 ^ (rr & 7);
        __builtin_amdgcn_global_load_lds(
            (GAS const u32*)(Kg + (size_t)(kb1 + rr) * QS + gg * 8),
            (LAS u32*)(Ktile[nb] + r0 * 64), 16, 0, 0);
        __builtin_amdgcn_global_load_lds(
            (GAS const u32*)(Vh + (size_t)rr * T + kb1 + gg * 8),
            (LAS u32*)(Vtile[nb] + r0 * 64), 16, 0, 0);
      }
    }
    const u16* Kt = Ktile[kt & 1];
    const u16* Vi = Vtile[kt & 1];
    const int kb = kt << 6;
    const int swz = fr & 7;
    v8s kf[4][2], vfr[4][2];
#pragma unroll
    for (int ks = 0; ks < 4; ++ks) {
      const int rr = ks * 16 + fr;
      kf[ks][0] = *(const v8s*)&Kt[rr * 64 + ((0 + fg) ^ swz) * 8];
      kf[ks][1] = *(const v8s*)&Kt[rr * 64 + ((4 + fg) ^ swz) * 8];
      vfr[ks][0] = *(const v8s*)&Vi[rr * 64 + ((0 + fg) ^ swz) * 8];
      vfr[ks][1] = *(const v8s*)&Vi[rr * 64 + ((4 + fg) ^ swz) * 8];
    }
    if (kt < ta) {
      attn_sub_pair<false>(kf, vfr, qfA, qfB, otA, otB, mA, lA, mB, lB,
                           pwA, pwB, kb, rowA, rowB, fr, fg);
    } else if (kt == ta) {
      attn_sub_pair<true>(kf, vfr, qfA, qfB, otA, otB, mA, lA, mB, lB,
                          pwA, pwB, kb, rowA, rowB, fr, fg);
    } else if (kt < tb) {
      attn_sub<false>(kf, vfr, qfB, otB, mB, lB, pwB, kb, rowB, fr, fg);
    } else {
      attn_sub<true>(kf, vfr, qfB, otB, mB, lB, pwB, kb, rowB, fr, fg);
    }
  }

  const float invA = 1.f / lA, invB = 1.f / lB;
#pragma unroll
  for (int ds = 0; ds < 4; ++ds) {
    uint2 pa, pb;
    pa.x = f2bf2(otA[ds][0] * invA, otA[ds][1] * invA);
    pa.y = f2bf2(otA[ds][2] * invA, otA[ds][3] * invA);
    pb.x = f2bf2(otB[ds][0] * invB, otB[ds][1] * invB);
    pb.y = f2bf2(otB[ds][2] * invB, otB[ds][3] * invB);
    *(uint2*)&y[(size_t)(b * T + rowA + fr) * C + h * D + ds * 16 + fg * 4] = pa;
    *(uint2*)&y[(size_t)(b * T + rowB + fr) * C + h * D + ds * 16 + fg * 4] = pb;
  }
}

// ------------------------------- launch ----------------------------------
extern "C" void kernel_launch(void* const* d_in, const int* in_sizes, int n_in,
                              void* d_out, int out_size, void* d_ws, size_t ws_size,
                              hipStream_t stream) {
  const float* x      = (const float*)d_in[0];
  const float* ln1_g  = (const float*)d_in[1];
  const float* ln1_b  = (const float*)d_in[2];
  const float* W_attn = (const float*)d_in[3];
  const float* b_attn = (const float*)d_in[4];
  const float* W_o    = (const float*)d_in[5];
  const float* b_o    = (const float*)d_in[6];
  const float* ln2_g  = (const float*)d_in[7];
  const float* ln2_b  = (const float*)d_in[8];
  const float* W_fc   = (const float*)d_in[9];
  const float* b_fc   = (const float*)d_in[10];
  const float* W_fc2  = (const float*)d_in[11];
  const float* b_fc2  = (const float*)d_in[12];
  float* out = (float*)d_out;
  char* ws = (char*)d_ws;

  const size_t MB = 1u << 20;
  u16* Wattn_t = (u16*)(ws + 0 * MB);   // 6MB
  u16* Wo_t    = (u16*)(ws + 6 * MB);   // 2MB
  u16* Wfc_t   = (u16*)(ws + 8 * MB);   // 8MB
  u16* Wfc2_t  = (u16*)(ws + 16 * MB);  // 8MB
  float* x1    = (float*)(ws + 24 * MB); // 16MB
  u16* h1      = (u16*)(ws + 40 * MB);  // 8MB
  u16* qkv     = (u16*)(ws + 48 * MB);  // 24MB (alive through attn)
  u16* Vt      = (u16*)(ws + 88 * MB);  // 8MB
  u16* yb      = (u16*)(ws + 40 * MB);  // reuse h1 (dead after qkv GEMM)
  u16* h2      = (u16*)(ws + 48 * MB);  // reuse qkv (dead after attn)
  u16* ab      = (u16*)(ws + 56 * MB);  // 32MB (56..88)

  wtrans<<<dim3(3072 / 32, 1024 / 32), 256, 0, stream>>>(W_attn, Wattn_t, 1024, 3072);
  wtrans<<<dim3(1024 / 32, 1024 / 32), 256, 0, stream>>>(W_o, Wo_t, 1024, 1024);
  wtrans<<<dim3(4096 / 32, 1024 / 32), 256, 0, stream>>>(W_fc, Wfc_t, 1024, 4096);
  wtrans<<<dim3(1024 / 32, 4096 / 32), 256, 0, stream>>>(W_fc2, Wfc2_t, 4096, 1024);

  ln_bf16<<<4096, 256, 0, stream>>>(x, ln1_g, ln1_b, h1);
  gemm_bt_p<0, 1><<<dim3(3072 / 128, 4096 / 128), 256, 0, stream>>>(
      h1, Wattn_t, b_attn, nullptr, qkv, 4096, 3072, 1024);
  transpose_v<<<dim3(2048 / 64, 32), 256, 0, stream>>>(qkv, Vt);
  attn_kernel<<<dim3(16, 32), 256, 0, stream>>>(qkv, Vt, yb);
  gemm_bt_n64<2><<<dim3(1024 / 64, 4096 / 128), 256, 0, stream>>>(
      yb, Wo_t, b_o, x, x1, 4096, 1024, 1024);
  ln_bf16<<<4096, 256, 0, stream>>>(x1, ln2_g, ln2_b, h2);
  gemm_bt_p<1, 1><<<dim3(4096 / 128, 4096 / 128), 256, 0, stream>>>(
      h2, Wfc_t, b_fc, nullptr, ab, 4096, 4096, 1024);
  gemm_bt_p<2, 1><<<dim3(1024 / 128, 4096 / 128), 256, 0, stream>>>(
      ab, Wfc2_t, b_fc2, x1, out, 4096, 1024, 4096);
}

// Round 10
// 334.276 us; speedup vs baseline: 1.0532x; 1.0271x over previous
//
#include <hip/hip_runtime.h>

// Transformer block on MI355X (gfx950).
// B=2, T=2048, C=1024, H=16, D=64. All GEMMs in bf16 MFMA (16x16x32).
// R5: attention causal pairing. R7/R8: asm ds_read + vmcnt pipelines.
// R11: fc2 XCD remap. R12: reg-pipelined frags. R13: attn VALU trim.
// R14: attn XCD remap + fused A/B pair. R15/R16: 3-buf + bank swizzle.
// R17: coarse 256^2 REGRESSED (1-barrier step at 1 block/CU: no overlap).
// R18: generic remap on fc1: FETCH 41->94MB yet dur FLAT -> GEMM is
//      NOT memory-bound; it's schedule-bound (m97-structure ceiling).
// R19: phase-split 256^2 for fc1 only (grid 16x16 = exactly 1 block/CU):
//      each BK=32 step = 2 phases {stage-issue, ds_reads, lgkm, setprio,
//      16 MFMA} | barrier | {...}. Per-phase barriers put the SIMD's 2
//      waves in DIFFERENT phases -> reads overlap MFMAs (T3 mechanism);
//      setprio now has a role split to arbitrate (T5: +21-39% only on
//      phase-split schedules, m218b). qkv back to 128^2 REMAP=0 (R16).

typedef unsigned short u16;
typedef unsigned int u32;
typedef __attribute__((ext_vector_type(8))) short v8s;   // 8 x bf16 (4 VGPR)
typedef __attribute__((ext_vector_type(4))) float v4f;   // MFMA acc

#define GAS __attribute__((address_space(1)))
#define LAS __attribute__((address_space(3)))

__device__ __forceinline__ u16 f2bf(float f) {
  u32 u = __float_as_uint(f);
  u = (u + 0x7FFF + ((u >> 16) & 1)) >> 16;  // RNE
  return (u16)u;
}
__device__ __forceinline__ u32 f2bf2(float lo, float hi) {
  u32 r;
  asm("v_cvt_pk_bf16_f32 %0, %1, %2" : "=v"(r) : "v"(lo), "v"(hi));
  return r;
}
__device__ __forceinline__ float exp2g(float x) {
  return __builtin_amdgcn_exp2f(x);  // v_exp_f32: native 2^x
}
__device__ __forceinline__ float bf2f(u16 h) {
  return __uint_as_float(((u32)h) << 16);
}
__device__ __forceinline__ float fast_tanh(float x) {
  return 1.f - 2.f / (1.f + __expf(2.f * x));
}

// ---------------- weight transpose + fp32->bf16 convert ----------------
__global__ __launch_bounds__(256)
void wtrans(const float* __restrict__ W, u16* __restrict__ Wt, int K, int N) {
  __shared__ float tile[32][33];
  const int n0 = blockIdx.x << 5, k0 = blockIdx.y << 5;
  const int r = threadIdx.x >> 5, c = threadIdx.x & 31;
#pragma unroll
  for (int i = 0; i < 4; ++i)
    tile[r + 8 * i][c] = W[(size_t)(k0 + r + 8 * i) * N + n0 + c];
  __syncthreads();
#pragma unroll
  for (int i = 0; i < 4; ++i)
    Wt[(size_t)(n0 + r + 8 * i) * K + k0 + c] = f2bf(tile[c][r + 8 * i]);
}

// ---------------- LayerNorm (f32 in -> bf16 out), C=1024 ----------------
__global__ __launch_bounds__(256)
void ln_bf16(const float* __restrict__ x, const float* __restrict__ g,
             const float* __restrict__ be, u16* __restrict__ out) {
  constexpr int C = 1024;
  const int row = blockIdx.x, t = threadIdx.x;
  const float4 v = ((const float4*)(x + (size_t)row * C))[t];
  float s = v.x + v.y + v.z + v.w;
#pragma unroll
  for (int m = 32; m >= 1; m >>= 1) s += __shfl_xor(s, m);
  __shared__ float red[4], red2[4];
  if ((t & 63) == 0) red[t >> 6] = s;
  __syncthreads();
  const float mu = (red[0] + red[1] + red[2] + red[3]) * (1.f / C);
  const float dx = v.x - mu, dy = v.y - mu, dz = v.z - mu, dw = v.w - mu;
  float s2 = dx * dx + dy * dy + dz * dz + dw * dw;
#pragma unroll
  for (int m = 32; m >= 1; m >>= 1) s2 += __shfl_xor(s2, m);
  if ((t & 63) == 0) red2[t >> 6] = s2;
  __syncthreads();
  const float var = (red2[0] + red2[1] + red2[2] + red2[3]) * (1.f / C);
  const float rs = rsqrtf(var + 1e-5f);
  const int c = t << 2;
  uint2 pk;
  pk.x = f2bf2(dx * rs * g[c + 0] + be[c + 0], dy * rs * g[c + 1] + be[c + 1]);
  pk.y = f2bf2(dz * rs * g[c + 2] + be[c + 2], dw * rs * g[c + 3] + be[c + 3]);
  *(uint2*)(out + (size_t)row * C + c) = pk;
}

// ------- GEMM 256x256, 8 waves, BK=32, 4 bufs, 2-PHASE schedule (fc1) ----
// Per K-step: vmcnt(8), barrier, {issue A-stage(kt+3), rd a0-3 b0-3,
// lgkm, prio1, 16 MFMA, prio0}, barrier, {issue B-stage(kt+3), rd a4-7,
// lgkm, prio1, 16 MFMA, prio0}. Buf (kt+3)&3 == (kt-1)&3 is rewritten
// only after the top barrier that follows all reads of it.
template <int EPI>
__global__ __launch_bounds__(512, 2)
void gemm_bt_p256b(const u16* __restrict__ A, const u16* __restrict__ Bt,
                   const float* __restrict__ bias, const float* __restrict__ res,
                   void* __restrict__ outp, int M, int N, int K) {
  __shared__ u16 As[4][256 * 32];
  __shared__ u16 Bs[4][256 * 32];
  const int tid = threadIdx.x;
  const int wave = tid >> 6, lane = tid & 63;
  const int m0 = blockIdx.y << 8, n0 = blockIdx.x << 8;

  v4f acc[8][4];
  const v4f vz = {0.f, 0.f, 0.f, 0.f};
#pragma unroll
  for (int i = 0; i < 8; ++i)
#pragma unroll
    for (int j = 0; j < 4; ++j) acc[i][j] = vz;

  const int wm = (wave >> 2) << 7;     // 0 or 128
  const int wn = (wave & 3) << 6;      // 0,64,128,192
  const int fr = lane & 15;
  const int fg = lane >> 4;

  // staging: thread t covers row t>>2, swizzled 16B chunk; rows 0..127 in
  // instr0, 128..255 in instr1. LDS dest linear (wave-uniform base+lane*16).
  const int sr = tid >> 2;
  const int sc = (((tid & 3) ^ ((tid >> 4) & 3)) << 3);
  const u16* gA0 = A + (size_t)(m0 + sr) * K + sc;
  const u16* gA1 = gA0 + (size_t)128 * K;
  const u16* gB0 = Bt + (size_t)(n0 + sr) * K + sc;
  const u16* gB1 = gB0 + (size_t)128 * K;
  const int aoff = wave * 512;         // u16 elems (wave = 16 rows = 1KB)

  const u32 asb = (u32)(size_t)(LAS const u16*)&As[0][0];
  const u32 bsb = (u32)(size_t)(LAS const u16*)&Bs[0][0];
  const int cgp = fg ^ ((fr >> 2) & 3);  // swizzled read chunk
  const u32 afrag = (u32)(((wm + fr) << 6) + (cgp << 4));  // bytes
  const u32 bfrag = (u32)(((wn + fr) << 6) + (cgp << 4));

  const int nk = K >> 5;  // 32

#define PI_A(t, bf)                                                               \
  do {                                                                            \
    const int k0_ = (t) << 5;                                                     \
    __builtin_amdgcn_global_load_lds((GAS const u32*)(gA0 + k0_),                 \
                                     (LAS u32*)(As[bf] + aoff), 16, 0, 0);        \
    __builtin_amdgcn_global_load_lds((GAS const u32*)(gA1 + k0_),                 \
                                     (LAS u32*)(As[bf] + aoff + 4096), 16, 0, 0); \
  } while (0)
#define PI_B(t, bf)                                                               \
  do {                                                                            \
    const int k0_ = (t) << 5;                                                     \
    __builtin_amdgcn_global_load_lds((GAS const u32*)(gB0 + k0_),                 \
                                     (LAS u32*)(Bs[bf] + aoff), 16, 0, 0);        \
    __builtin_amdgcn_global_load_lds((GAS const u32*)(gB1 + k0_),                 \
                                     (LAS u32*)(Bs[bf] + aoff + 4096), 16, 0, 0); \
  } while (0)

  v8s a[8], b[4];
  auto rd0 = [&](int buf) __attribute__((always_inline)) {
    const u32 ab = asb + ((u32)buf << 14) + afrag;  // buf stride 16 KB
    const u32 bb = bsb + ((u32)buf << 14) + bfrag;
    asm volatile("ds_read_b128 %0, %1 offset:0"    : "=v"(a[0]) : "v"(ab));
    asm volatile("ds_read_b128 %0, %1 offset:1024" : "=v"(a[1]) : "v"(ab));
    asm volatile("ds_read_b128 %0, %1 offset:2048" : "=v"(a[2]) : "v"(ab));
    asm volatile("ds_read_b128 %0, %1 offset:3072" : "=v"(a[3]) : "v"(ab));
    asm volatile("ds_read_b128 %0, %1 offset:0"    : "=v"(b[0]) : "v"(bb));
    asm volatile("ds_read_b128 %0, %1 offset:1024" : "=v"(b[1]) : "v"(bb));
    asm volatile("ds_read_b128 %0, %1 offset:2048" : "=v"(b[2]) : "v"(bb));
    asm volatile("ds_read_b128 %0, %1 offset:3072" : "=v"(b[3]) : "v"(bb));
    asm volatile("s_waitcnt lgkmcnt(0)"
                 : "+v"(a[0]), "+v"(a[1]), "+v"(a[2]), "+v"(a[3]),
                   "+v"(b[0]), "+v"(b[1]), "+v"(b[2]), "+v"(b[3])
                 :
                 : "memory");
  };
  auto rd1 = [&](int buf) __attribute__((always_inline)) {
    const u32 ab = asb + ((u32)buf << 14) + afrag;
    asm volatile("ds_read_b128 %0, %1 offset:4096" : "=v"(a[4]) : "v"(ab));
    asm volatile("ds_read_b128 %0, %1 offset:5120" : "=v"(a[5]) : "v"(ab));
    asm volatile("ds_read_b128 %0, %1 offset:6144" : "=v"(a[6]) : "v"(ab));
    asm volatile("ds_read_b128 %0, %1 offset:7168" : "=v"(a[7]) : "v"(ab));
    asm volatile("s_waitcnt lgkmcnt(0)"
                 : "+v"(a[4]), "+v"(a[5]), "+v"(a[6]), "+v"(a[7])
                 :
                 : "memory");
  };
  auto mfma03 = [&]() __attribute__((always_inline)) {
    __builtin_amdgcn_s_setprio(1);
#pragma unroll
    for (int i = 0; i < 4; ++i)
#pragma unroll
      for (int j = 0; j < 4; ++j)
        acc[i][j] = __builtin_amdgcn_mfma_f32_16x16x32_bf16(a[i], b[j], acc[i][j], 0, 0, 0);
    __builtin_amdgcn_s_setprio(0);
  };
  auto mfma47 = [&]() __attribute__((always_inline)) {
    __builtin_amdgcn_s_setprio(1);
#pragma unroll
    for (int i = 4; i < 8; ++i)
#pragma unroll
      for (int j = 0; j < 4; ++j)
        acc[i][j] = __builtin_amdgcn_mfma_f32_16x16x32_bf16(a[i], b[j], acc[i][j], 0, 0, 0);
    __builtin_amdgcn_s_setprio(0);
  };

  PI_A(0, 0); PI_B(0, 0);
  PI_A(1, 1); PI_B(1, 1);
  PI_A(2, 2); PI_B(2, 2);

  for (int kt = 0; kt < nk - 2; ++kt) {
    asm volatile("s_waitcnt vmcnt(8)" ::: "memory");  // tile kt resident
    __builtin_amdgcn_s_barrier();
    if (kt + 3 < nk) PI_A(kt + 3, (kt + 3) & 3);
    rd0(kt & 3);
    mfma03();
    __builtin_amdgcn_s_barrier();
    if (kt + 3 < nk) PI_B(kt + 3, (kt + 3) & 3);
    rd1(kt & 3);
    mfma47();
  }
  // kt = nk-2 (outstanding: tiles nk-2, nk-1 = 8 loads)
  asm volatile("s_waitcnt vmcnt(4)" ::: "memory");
  __builtin_amdgcn_s_barrier();
  rd0((nk - 2) & 3);
  mfma03();
  __builtin_amdgcn_s_barrier();
  rd1((nk - 2) & 3);
  mfma47();
  // kt = nk-1
  asm volatile("s_waitcnt vmcnt(0)" ::: "memory");
  __builtin_amdgcn_s_barrier();
  rd0((nk - 1) & 3);
  mfma03();
  __builtin_amdgcn_s_barrier();
  rd1((nk - 1) & 3);
  mfma47();
#undef PI_A
#undef PI_B

  const int er = (lane >> 4) << 2;
#pragma unroll
  for (int mi = 0; mi < 8; ++mi) {
#pragma unroll
    for (int ni = 0; ni < 4; ++ni) {
      const int col = n0 + wn + ni * 16 + fr;
      const float bcol = bias[col];
#pragma unroll
      for (int r = 0; r < 4; ++r) {
        const int row = m0 + wm + mi * 16 + er + r;
        float v = acc[mi][ni][r] + bcol;
        if constexpr (EPI == 1) {
          const float t = fast_tanh(0.7978845608028654f * (v + 0.044715f * v * v * v));
          v = 0.5f * v * (1.f + t);
        }
        if constexpr (EPI == 2) {
          v += res[(size_t)row * N + col];
          ((float*)outp)[(size_t)row * N + col] = v;
        } else {
          ((u16*)outp)[(size_t)row * N + col] = f2bf(v);
        }
      }
    }
  }
}

// ------- GEMM 128x128, depth-3, 3 LDS buffers, reg-pipelined, swizzled ---
// REMAP=1: XCD-aware tile remap (requires gridDim.y % 8 == 0).
template <int EPI, int REMAP>
__global__ __launch_bounds__(256)
void gemm_bt_p(const u16* __restrict__ A, const u16* __restrict__ Bt,
               const float* __restrict__ bias, const float* __restrict__ res,
               void* __restrict__ outp, int M, int N, int K) {
  __shared__ u16 As[3][128 * 32];
  __shared__ u16 Bs[3][128 * 32];
  const int tid = threadIdx.x;
  const int wave = tid >> 6, lane = tid & 63;
  int bx, by;
  if constexpr (REMAP) {
    const int gx = (int)gridDim.x;
    const int wg = blockIdx.y * gx + blockIdx.x;
    const int xcd = wg & 7;
    const int q = wg >> 3;
    bx = q % gx;
    by = xcd + ((q / gx) << 3);
  } else {
    bx = blockIdx.x;
    by = blockIdx.y;
  }
  const int m0 = by << 7, n0 = bx << 7;

  v4f acc[4][4];
  const v4f vz = {0.f, 0.f, 0.f, 0.f};
#pragma unroll
  for (int i = 0; i < 4; ++i)
#pragma unroll
    for (int j = 0; j < 4; ++j) acc[i][j] = vz;

  const int wm = (wave >> 1) << 6, wn = (wave & 1) << 6;
  const int sr = lane >> 2;
  const int sc = (((lane & 3) ^ ((lane >> 4) & 3)) << 3);
  const int fr = lane & 15;
  const int fg = lane >> 4;
  const int c0 = wave << 1;

  const u16* gA0 = A + (size_t)(m0 + c0 * 16 + sr) * K + sc;
  const u16* gA1 = A + (size_t)(m0 + c0 * 16 + 16 + sr) * K + sc;
  const u16* gB0 = Bt + (size_t)(n0 + c0 * 16 + sr) * K + sc;
  const u16* gB1 = Bt + (size_t)(n0 + c0 * 16 + 16 + sr) * K + sc;
  const int aoff = c0 * 512;  // elements within a buffer

  const u32 asb = (u32)(size_t)(LAS const u16*)&As[0][0];
  const u32 bsb = (u32)(size_t)(LAS const u16*)&Bs[0][0];
  const int cgp = fg ^ ((fr >> 2) & 3);
  const u32 afrag = (u32)(((wm + fr) << 6) + (cgp << 4));  // bytes
  const u32 bfrag = (u32)(((wn + fr) << 6) + (cgp << 4));

  const int nk = K >> 5;  // even, >= 4

#define P128_ISSUE(t, bf)                                                        \
  do {                                                                           \
    const int k0_ = (t) << 5;                                                    \
    __builtin_amdgcn_global_load_lds((GAS const u32*)(gA0 + k0_),                \
                                     (LAS u32*)(As[bf] + aoff), 16, 0, 0);       \
    __builtin_amdgcn_global_load_lds((GAS const u32*)(gA1 + k0_),                \
                                     (LAS u32*)(As[bf] + aoff + 512), 16, 0, 0); \
    __builtin_amdgcn_global_load_lds((GAS const u32*)(gB0 + k0_),                \
                                     (LAS u32*)(Bs[bf] + aoff), 16, 0, 0);       \
    __builtin_amdgcn_global_load_lds((GAS const u32*)(gB1 + k0_),                \
                                     (LAS u32*)(Bs[bf] + aoff + 512), 16, 0, 0); \
  } while (0)

  auto ldfr = [&](int buf, v8s (&a)[4], v8s (&b)[4]) __attribute__((always_inline)) {
    const u32 ab = asb + ((u32)buf << 13) + afrag;  // buf stride 8 KB
    const u32 bb = bsb + ((u32)buf << 13) + bfrag;
    asm volatile("ds_read_b128 %0, %1 offset:0"    : "=v"(a[0]) : "v"(ab));
    asm volatile("ds_read_b128 %0, %1 offset:1024" : "=v"(a[1]) : "v"(ab));
    asm volatile("ds_read_b128 %0, %1 offset:2048" : "=v"(a[2]) : "v"(ab));
    asm volatile("ds_read_b128 %0, %1 offset:3072" : "=v"(a[3]) : "v"(ab));
    asm volatile("ds_read_b128 %0, %1 offset:0"    : "=v"(b[0]) : "v"(bb));
    asm volatile("ds_read_b128 %0, %1 offset:1024" : "=v"(b[1]) : "v"(bb));
    asm volatile("ds_read_b128 %0, %1 offset:2048" : "=v"(b[2]) : "v"(bb));
    asm volatile("ds_read_b128 %0, %1 offset:3072" : "=v"(b[3]) : "v"(bb));
  };
  auto wait8 = [&](v8s (&a)[4], v8s (&b)[4]) __attribute__((always_inline)) {
    asm volatile("s_waitcnt lgkmcnt(0)"
                 : "+v"(a[0]), "+v"(a[1]), "+v"(a[2]), "+v"(a[3]),
                   "+v"(b[0]), "+v"(b[1]), "+v"(b[2]), "+v"(b[3])
                 :
                 : "memory");
  };
  auto mfma16 = [&](v8s (&a)[4], v8s (&b)[4]) __attribute__((always_inline)) {
#pragma unroll
    for (int i = 0; i < 4; ++i)
#pragma unroll
      for (int j = 0; j < 4; ++j)
        acc[i][j] = __builtin_amdgcn_mfma_f32_16x16x32_bf16(a[i], b[j], acc[i][j], 0, 0, 0);
  };

  v8s aX[4], bX[4], aY[4], bY[4];

  P128_ISSUE(0, 0);
  P128_ISSUE(1, 1);
  P128_ISSUE(2, 2);
  asm volatile("s_waitcnt vmcnt(8)" ::: "memory");  // tile 0 resident
  __builtin_amdgcn_s_barrier();
  ldfr(0, aX, bX);
  wait8(aX, bX);

  int br = 1, bi = 0;
  for (int kt = 0; kt < nk - 2; kt += 2) {
    asm volatile("s_waitcnt vmcnt(4)" ::: "memory");  // tile kt+1 resident
    __builtin_amdgcn_s_barrier();
    ldfr(br, aY, bY);
    if (kt + 3 < nk) P128_ISSUE(kt + 3, bi);
    __builtin_amdgcn_sched_barrier(0);
    mfma16(aX, bX);
    wait8(aY, bY);
    br = (br == 2) ? 0 : br + 1;
    bi = (bi == 2) ? 0 : bi + 1;
    asm volatile("s_waitcnt vmcnt(4)" ::: "memory");
    __builtin_amdgcn_s_barrier();
    ldfr(br, aX, bX);
    if (kt + 4 < nk) P128_ISSUE(kt + 4, bi);
    __builtin_amdgcn_sched_barrier(0);
    mfma16(aY, bY);
    wait8(aX, bX);
    br = (br == 2) ? 0 : br + 1;
    bi = (bi == 2) ? 0 : bi + 1;
  }
  asm volatile("s_waitcnt vmcnt(0)" ::: "memory");
  __builtin_amdgcn_s_barrier();
  ldfr(br, aY, bY);
  __builtin_amdgcn_sched_barrier(0);
  mfma16(aX, bX);
  wait8(aY, bY);
  mfma16(aY, bY);
#undef P128_ISSUE

  const int er = (lane >> 4) << 2;
#pragma unroll
  for (int mi = 0; mi < 4; ++mi) {
#pragma unroll
    for (int ni = 0; ni < 4; ++ni) {
      const int col = n0 + wn + ni * 16 + fr;
      const float bcol = bias[col];
#pragma unroll
      for (int r = 0; r < 4; ++r) {
        const int row = m0 + wm + mi * 16 + er + r;
        float v = acc[mi][ni][r] + bcol;
        if constexpr (EPI == 1) {
          const float t = fast_tanh(0.7978845608028654f * (v + 0.044715f * v * v * v));
          v = 0.5f * v * (1.f + t);
        }
        if constexpr (EPI == 2) {
          v += res[(size_t)row * N + col];
          ((float*)outp)[(size_t)row * N + col] = v;
        } else {
          ((u16*)outp)[(size_t)row * N + col] = f2bf(v);
        }
      }
    }
  }
}

// ------- GEMM 128x64, depth-3 prefetch, asm ds_read, swizzled (proj) -----
template <int EPI>
__global__ __launch_bounds__(256)
void gemm_bt_n64(const u16* __restrict__ A, const u16* __restrict__ Bt,
                 const float* __restrict__ bias, const float* __restrict__ res,
                 void* __restrict__ outp, int M, int N, int K) {
  __shared__ u16 As[4][128 * 32];
  __shared__ u16 Bs[4][64 * 32];
  const int tid = threadIdx.x;
  const int wave = tid >> 6, lane = tid & 63;
  const int m0 = blockIdx.y << 7, n0 = blockIdx.x << 6;

  v4f acc[4][2];
  const v4f vz = {0.f, 0.f, 0.f, 0.f};
#pragma unroll
  for (int i = 0; i < 4; ++i)
#pragma unroll
    for (int j = 0; j < 2; ++j) acc[i][j] = vz;

  const int wm = (wave >> 1) << 6, wn = (wave & 1) << 5;
  const int sr = lane >> 2;
  const int sc = (((lane & 3) ^ ((lane >> 4) & 3)) << 3);  // R16 swizzle
  const int fr = lane & 15;
  const int fg = lane >> 4;

  const u16* gA0 = A + (size_t)(m0 + wave * 32 + sr) * K + sc;
  const u16* gA1 = A + (size_t)(m0 + wave * 32 + 16 + sr) * K + sc;
  const u16* gB0 = Bt + (size_t)(n0 + wave * 16 + sr) * K + sc;
  const int aoff = wave * 1024;
  const int boff = wave * 512;

  const u32 asb = (u32)(size_t)(LAS const u16*)&As[0][0];
  const u32 bsb = (u32)(size_t)(LAS const u16*)&Bs[0][0];
  const int cgp = fg ^ ((fr >> 2) & 3);
  const u32 afrag = (u32)(((wm + fr) << 6) + (cgp << 4));
  const u32 bfrag = (u32)(((wn + fr) << 6) + (cgp << 4));

  const int nk = K >> 5;

#define N64_ISSUE(t, bf)                                                      \
  do {                                                                        \
    const int k0_ = (t) << 5;                                                 \
    __builtin_amdgcn_global_load_lds((GAS const u32*)(gA0 + k0_),             \
                                     (LAS u32*)(As[bf] + aoff), 16, 0, 0);    \
    __builtin_amdgcn_global_load_lds((GAS const u32*)(gA1 + k0_),             \
                                     (LAS u32*)(As[bf] + aoff + 512), 16, 0, 0); \
    __builtin_amdgcn_global_load_lds((GAS const u32*)(gB0 + k0_),             \
                                     (LAS u32*)(Bs[bf] + boff), 16, 0, 0);    \
  } while (0)

  N64_ISSUE(0, 0);
  N64_ISSUE(1, 1);
  N64_ISSUE(2, 2);

  auto compute = [&](int kt) __attribute__((always_inline)) {
    const u32 ab = asb + ((u32)(kt & 3) << 13) + afrag;  // A buf stride 8 KB
    const u32 bb = bsb + ((u32)(kt & 3) << 12) + bfrag;  // B buf stride 4 KB
    v8s a0, a1, a2, a3, b0, b1;
    asm volatile("ds_read_b128 %0, %1 offset:0"    : "=v"(a0) : "v"(ab));
    asm volatile("ds_read_b128 %0, %1 offset:1024" : "=v"(a1) : "v"(ab));
    asm volatile("ds_read_b128 %0, %1 offset:2048" : "=v"(a2) : "v"(ab));
    asm volatile("ds_read_b128 %0, %1 offset:3072" : "=v"(a3) : "v"(ab));
    asm volatile("ds_read_b128 %0, %1 offset:0"    : "=v"(b0) : "v"(bb));
    asm volatile("ds_read_b128 %0, %1 offset:1024" : "=v"(b1) : "v"(bb));
    asm volatile("s_waitcnt lgkmcnt(0)"
                 : "+v"(a0), "+v"(a1), "+v"(a2), "+v"(a3), "+v"(b0), "+v"(b1)
                 :
                 : "memory");
    acc[0][0] = __builtin_amdgcn_mfma_f32_16x16x32_bf16(a0, b0, acc[0][0], 0, 0, 0);
    acc[0][1] = __builtin_amdgcn_mfma_f32_16x16x32_bf16(a0, b1, acc[0][1], 0, 0, 0);
    acc[1][0] = __builtin_amdgcn_mfma_f32_16x16x32_bf16(a1, b0, acc[1][0], 0, 0, 0);
    acc[1][1] = __builtin_amdgcn_mfma_f32_16x16x32_bf16(a1, b1, acc[1][1], 0, 0, 0);
    acc[2][0] = __builtin_amdgcn_mfma_f32_16x16x32_bf16(a2, b0, acc[2][0], 0, 0, 0);
    acc[2][1] = __builtin_amdgcn_mfma_f32_16x16x32_bf16(a2, b1, acc[2][1], 0, 0, 0);
    acc[3][0] = __builtin_amdgcn_mfma_f32_16x16x32_bf16(a3, b0, acc[3][0], 0, 0, 0);
    acc[3][1] = __builtin_amdgcn_mfma_f32_16x16x32_bf16(a3, b1, acc[3][1], 0, 0, 0);
  };

  for (int kt = 0; kt < nk - 2; ++kt) {
    asm volatile("s_waitcnt vmcnt(6)" ::: "memory");
    __builtin_amdgcn_s_barrier();
    if (kt + 3 < nk) N64_ISSUE(kt + 3, (kt + 3) & 3);
    compute(kt);
  }
  asm volatile("s_waitcnt vmcnt(3)" ::: "memory");
  __builtin_amdgcn_s_barrier();
  compute(nk - 2);
  asm volatile("s_waitcnt vmcnt(0)" ::: "memory");
  __builtin_amdgcn_s_barrier();
  compute(nk - 1);
#undef N64_ISSUE

  const int er = (lane >> 4) << 2;
#pragma unroll
  for (int mi = 0; mi < 4; ++mi) {
#pragma unroll
    for (int ni = 0; ni < 2; ++ni) {
      const int col = n0 + wn + ni * 16 + fr;
      const float bcol = bias[col];
#pragma unroll
      for (int r = 0; r < 4; ++r) {
        const int row = m0 + wm + mi * 16 + er + r;
        float v = acc[mi][ni][r] + bcol;
        if constexpr (EPI == 1) {
          const float t = fast_tanh(0.7978845608028654f * (v + 0.044715f * v * v * v));
          v = 0.5f * v * (1.f + t);
        }
        if constexpr (EPI == 2) {
          v += res[(size_t)row * N + col];
          ((float*)outp)[(size_t)row * N + col] = v;
        } else {
          ((u16*)outp)[(size_t)row * N + col] = f2bf(v);
        }
      }
    }
  }
}

// ---------------- V -> Vt [B,H,D,T] bf16 (transpose via LDS) -------------
__global__ __launch_bounds__(256)
void transpose_v(const u16* __restrict__ qkv, u16* __restrict__ Vt) {
  __shared__ u16 tile[64][65];
  const int t0 = blockIdx.x << 6;
  const int bh = blockIdx.y;
  const int b = bh >> 4, h = bh & 15;
  const int r4 = threadIdx.x >> 6, c = threadIdx.x & 63;
#pragma unroll
  for (int i = 0; i < 16; ++i) {
    const int r = r4 * 16 + i;
    tile[r][c] = qkv[(size_t)(b * 2048 + t0 + r) * 3072 + 2048 + h * 64 + c];
  }
  __syncthreads();
#pragma unroll
  for (int i = 0; i < 16; ++i) {
    const int d = r4 * 16 + i;
    Vt[(size_t)bh * 64 * 2048 + (size_t)d * 2048 + t0 + c] = tile[c][d];
  }
}

// ---------------- flash attention (causal, balanced pairing) -------------
constexpr int PSTR = 88;  // P row stride (u16): 176B = 16B-mult, 2-way banks
constexpr float ATT_SC = 0.18033688011112042f;  // (1/8) * log2(e)

template <bool MASKED>
__device__ __forceinline__ void soft16(
    const v4f (&st)[4], float (&e)[4][4], v4f (&ot)[4],
    float& m_i, float& l_i, const int kb, const int qrow,
    const int fr, const int fg) {
  const int q = qrow + fr;
#pragma unroll
  for (int ks = 0; ks < 4; ++ks) {
    const v4f sv = st[ks] * ATT_SC;
#pragma unroll
    for (int r = 0; r < 4; ++r) {
      float v = sv[r];
      if (MASKED) v = (kb + ks * 16 + fg * 4 + r <= q) ? v : -1e30f;
      e[ks][r] = v;
    }
  }
  float mk0 = fmaxf(fmaxf(e[0][0], e[0][1]), fmaxf(e[0][2], e[0][3]));
  float mk1 = fmaxf(fmaxf(e[1][0], e[1][1]), fmaxf(e[1][2], e[1][3]));
  float mk2 = fmaxf(fmaxf(e[2][0], e[2][1]), fmaxf(e[2][2], e[2][3]));
  float mk3 = fmaxf(fmaxf(e[3][0], e[3][1]), fmaxf(e[3][2], e[3][3]));
  float mt = fmaxf(fmaxf(mk0, mk1), fmaxf(mk2, mk3));
  mt = fmaxf(mt, __shfl_xor(mt, 16));
  mt = fmaxf(mt, __shfl_xor(mt, 32));
  if (__any(mt > m_i)) {  // EXACT: alpha==1 when false
    const float m_new = fmaxf(m_i, mt);
    const float alpha = exp2g(m_i - m_new);
    m_i = m_new;
    l_i *= alpha;
#pragma unroll
    for (int ds = 0; ds < 4; ++ds) ot[ds] *= alpha;
  }
#pragma unroll
  for (int ks = 0; ks < 4; ++ks)
#pragma unroll
    for (int r = 0; r < 4; ++r) e[ks][r] = exp2g(e[ks][r] - m_i);
  float s0 = (e[0][0] + e[0][1]) + (e[0][2] + e[0][3]);
  float s1 = (e[1][0] + e[1][1]) + (e[1][2] + e[1][3]);
  float s2 = (e[2][0] + e[2][1]) + (e[2][2] + e[2][3]);
  float s3 = (e[3][0] + e[3][1]) + (e[3][2] + e[3][3]);
  float ls = (s0 + s1) + (s2 + s3);
  ls += __shfl_xor(ls, 16);
  ls += __shfl_xor(ls, 32);
  l_i += ls;
}

__device__ __forceinline__ void pstore(const float (&e)[4][4],
                                       u16* __restrict__ pw,
                                       const int fr, const int fg) {
#pragma unroll
  for (int ks = 0; ks < 4; ++ks) {
    uint2 pk;
    pk.x = f2bf2(e[ks][0], e[ks][1]);
    pk.y = f2bf2(e[ks][2], e[ks][3]);
    *(uint2*)&pw[fr * PSTR + ks * 16 + fg * 4] = pk;
  }
}

__device__ __forceinline__ void pvacc(const v8s (&vfr)[4][2],
                                      const u16* __restrict__ pw,
                                      v4f (&ot)[4], const int fr, const int fg) {
  const v8s pf0 = *(const v8s*)&pw[fr * PSTR + fg * 8];
  const v8s pf1 = *(const v8s*)&pw[fr * PSTR + 32 + fg * 8];
  __builtin_amdgcn_s_setprio(1);
#pragma unroll
  for (int ds = 0; ds < 4; ++ds) {
    ot[ds] = __builtin_amdgcn_mfma_f32_16x16x32_bf16(vfr[ds][0], pf0, ot[ds], 0, 0, 0);
    ot[ds] = __builtin_amdgcn_mfma_f32_16x16x32_bf16(vfr[ds][1], pf1, ot[ds], 0, 0, 0);
  }
  __builtin_amdgcn_s_setprio(0);
}

template <bool MASKED>
__device__ __forceinline__ void attn_sub(
    const v8s (&kf)[4][2], const v8s (&vfr)[4][2], const v8s (&qf)[2],
    v4f (&ot)[4], float& m_i, float& l_i, u16* __restrict__ pw,
    const int kb, const int qrow, const int fr, const int fg) {
  const v4f vz = {0.f, 0.f, 0.f, 0.f};
  v4f st[4];
  __builtin_amdgcn_s_setprio(1);
#pragma unroll
  for (int ks = 0; ks < 4; ++ks) {
    st[ks] = vz;
    st[ks] = __builtin_amdgcn_mfma_f32_16x16x32_bf16(kf[ks][0], qf[0], st[ks], 0, 0, 0);
    st[ks] = __builtin_amdgcn_mfma_f32_16x16x32_bf16(kf[ks][1], qf[1], st[ks], 0, 0, 0);
  }
  __builtin_amdgcn_s_setprio(0);
  float e[4][4];
  soft16<MASKED>(st, e, ot, m_i, l_i, kb, qrow, fr, fg);
  pstore(e, pw, fr, fg);
  pvacc(vfr, pw, ot, fr, fg);
}

template <bool MASKA>
__device__ __forceinline__ void attn_sub_pair(
    const v8s (&kf)[4][2], const v8s (&vfr)[4][2],
    const v8s (&qfA)[2], const v8s (&qfB)[2],
    v4f (&otA)[4], v4f (&otB)[4],
    float& mA, float& lA, float& mB, float& lB,
    u16* __restrict__ pwA, u16* __restrict__ pwB,
    const int kb, const int rowA, const int rowB, const int fr, const int fg) {
  const v4f vz = {0.f, 0.f, 0.f, 0.f};
  v4f stA[4], stB[4];
  __builtin_amdgcn_s_setprio(1);
#pragma unroll
  for (int ks = 0; ks < 4; ++ks) {
    stA[ks] = vz;
    stA[ks] = __builtin_amdgcn_mfma_f32_16x16x32_bf16(kf[ks][0], qfA[0], stA[ks], 0, 0, 0);
    stA[ks] = __builtin_amdgcn_mfma_f32_16x16x32_bf16(kf[ks][1], qfA[1], stA[ks], 0, 0, 0);
  }
#pragma unroll
  for (int ks = 0; ks < 4; ++ks) {
    stB[ks] = vz;
    stB[ks] = __builtin_amdgcn_mfma_f32_16x16x32_bf16(kf[ks][0], qfB[0], stB[ks], 0, 0, 0);
    stB[ks] = __builtin_amdgcn_mfma_f32_16x16x32_bf16(kf[ks][1], qfB[1], stB[ks], 0, 0, 0);
  }
  __builtin_amdgcn_s_setprio(0);
  float eA[4][4];
  soft16<MASKA>(stA, eA, otA, mA, lA, kb, rowA, fr, fg);
  pstore(eA, pwA, fr, fg);
  float eB[4][4];
  soft16<false>(stB, eB, otB, mB, lB, kb, rowB, fr, fg);
  pvacc(vfr, pwA, otA, fr, fg);
  pstore(eB, pwB, fr, fg);
  pvacc(vfr, pwB, otB, fr, fg);
}

__global__ __launch_bounds__(256)
void attn_kernel(const u16* __restrict__ qkv, const u16* __restrict__ Vt,
                 u16* __restrict__ y) {
  constexpr int T = 2048, D = 64, C = 1024, QS = 3072;
  __shared__ alignas(16) u16 Ktile[2][64 * 64];
  __shared__ alignas(16) u16 Vtile[2][64 * 64];
  __shared__ alignas(16) u16 Pw[8][16 * PSTR];

  const int tid = threadIdx.x, wave = tid >> 6, lane = tid & 63;
  const int fr = lane & 15, fg = lane >> 4;
  const int wg = blockIdx.y * 16 + blockIdx.x;
  const int xcd = wg & 7, seq = wg >> 3;
  const int bh = ((seq & 3) << 3) + xcd;
  const int ta = seq >> 2, tb = 31 - ta;
  const int b = bh >> 4, h = bh & 15;
  const u16* qkvb = qkv + (size_t)b * T * QS + h * 64;  // Q base
  const u16* Kg = qkvb + 1024;                          // K base
  const u16* Vh = Vt + (size_t)bh * D * T;
  u16* pwA = &Pw[wave][0];
  u16* pwB = &Pw[4 + wave][0];

  const int rowA = ta * 64 + wave * 16;
  const int rowB = tb * 64 + wave * 16;

  v8s qfA[2], qfB[2];
#pragma unroll
  for (int dh = 0; dh < 2; ++dh) {
    qfA[dh] = *(const v8s*)&qkvb[(size_t)(rowA + fr) * QS + dh * 32 + fg * 8];
    qfB[dh] = *(const v8s*)&qkvb[(size_t)(rowB + fr) * QS + dh * 32 + fg * 8];
  }

  const v4f vz = {0.f, 0.f, 0.f, 0.f};
  v4f otA[4], otB[4];
#pragma unroll
  for (int ds = 0; ds < 4; ++ds) { otA[ds] = vz; otB[ds] = vz; }
  float mA = -1e30f, lA = 0.f, mB = -1e30f, lB = 0.f;

  const int srow = lane >> 3;
  const int sg0 = lane & 7;

  const int nt = tb + 1;
  {
#pragma unroll
    for (int cc = 0; cc < 2; ++cc) {
      const int r0 = wave * 16 + cc * 8;
      const int rr = r0 + srow;
      const int gg = sg0 ^ (rr & 7);
      __builtin_amdgcn_global_load_lds(
          (GAS const u32*)(Kg + (size_t)rr * QS + gg * 8),
          (LAS u32*)(Ktile[0] + r0 * 64), 16, 0, 0);
      __builtin_amdgcn_global_load_lds(
          (GAS const u32*)(Vh + (size_t)rr * T + gg * 8),
          (LAS u32*)(Vtile[0] + r0 * 64), 16, 0, 0);
    }
  }
  for (int kt = 0; kt < nt; ++kt) {
    __syncthreads();
    if (kt + 1 < nt) {
      const int kb1 = (kt + 1) << 6;
      const int nb = (kt + 1) & 1;
#pragma unroll
      for (int cc = 0; cc < 2; ++cc) {
        const int r0 = wave * 16 + cc * 8;
        const int rr = r0 + srow;
        const int gg = sg0 ^ (rr & 7);
        __builtin_amdgcn_global_load_lds(
            (GAS const u32*)(Kg + (size_t)(kb1 + rr) * QS + gg * 8),
            (LAS u32*)(Ktile[nb] + r0 * 64), 16, 0, 0);
        __builtin_amdgcn_global_load_lds(
            (GAS const u32*)(Vh + (size_t)rr * T + kb1 + gg * 8),
            (LAS u32*)(Vtile[nb] + r0 * 64), 16, 0, 0);
      }
    }
    const u16* Kt = Ktile[kt & 1];
    const u16* Vi = Vtile[kt & 1];
    const int kb = kt << 6;
    const int swz = fr & 7;
    v8s kf[4][2], vfr[4][2];
#pragma unroll
    for (int ks = 0; ks < 4; ++ks) {
      const int rr = ks * 16 + fr;
      kf[ks][0] = *(const v8s*)&Kt[rr * 64 + ((0 + fg) ^ swz) * 8];
      kf[ks][1] = *(const v8s*)&Kt[rr * 64 + ((4 + fg) ^ swz) * 8];
      vfr[ks][0] = *(const v8s*)&Vi[rr * 64 + ((0 + fg) ^ swz) * 8];
      vfr[ks][1] = *(const v8s*)&Vi[rr * 64 + ((4 + fg) ^ swz) * 8];
    }
    if (kt < ta) {
      attn_sub_pair<false>(kf, vfr, qfA, qfB, otA, otB, mA, lA, mB, lB,
                           pwA, pwB, kb, rowA, rowB, fr, fg);
    } else if (kt == ta) {
      attn_sub_pair<true>(kf, vfr, qfA, qfB, otA, otB, mA, lA, mB, lB,
                          pwA, pwB, kb, rowA, rowB, fr, fg);
    } else if (kt < tb) {
      attn_sub<false>(kf, vfr, qfB, otB, mB, lB, pwB, kb, rowB, fr, fg);
    } else {
      attn_sub<true>(kf, vfr, qfB, otB, mB, lB, pwB, kb, rowB, fr, fg);
    }
  }

  const float invA = 1.f / lA, invB = 1.f / lB;
#pragma unroll
  for (int ds = 0; ds < 4; ++ds) {
    uint2 pa, pb;
    pa.x = f2bf2(otA[ds][0] * invA, otA[ds][1] * invA);
    pa.y = f2bf2(otA[ds][2] * invA, otA[ds][3] * invA);
    pb.x = f2bf2(otB[ds][0] * invB, otB[ds][1] * invB);
    pb.y = f2bf2(otB[ds][2] * invB, otB[ds][3] * invB);
    *(uint2*)&y[(size_t)(b * T + rowA + fr) * C + h * D + ds * 16 + fg * 4] = pa;
    *(uint2*)&y[(size_t)(b * T + rowB + fr) * C + h * D + ds * 16 + fg * 4] = pb;
  }
}

// ------------------------------- launch ----------------------------------
extern "C" void kernel_launch(void* const* d_in, const int* in_sizes, int n_in,
                              void* d_out, int out_size, void* d_ws, size_t ws_size,
                              hipStream_t stream) {
  const float* x      = (const float*)d_in[0];
  const float* ln1_g  = (const float*)d_in[1];
  const float* ln1_b  = (const float*)d_in[2];
  const float* W_attn = (const float*)d_in[3];
  const float* b_attn = (const float*)d_in[4];
  const float* W_o    = (const float*)d_in[5];
  const float* b_o    = (const float*)d_in[6];
  const float* ln2_g  = (const float*)d_in[7];
  const float* ln2_b  = (const float*)d_in[8];
  const float* W_fc   = (const float*)d_in[9];
  const float* b_fc   = (const float*)d_in[10];
  const float* W_fc2  = (const float*)d_in[11];
  const float* b_fc2  = (const float*)d_in[12];
  float* out = (float*)d_out;
  char* ws = (char*)d_ws;

  const size_t MB = 1u << 20;
  u16* Wattn_t = (u16*)(ws + 0 * MB);   // 6MB
  u16* Wo_t    = (u16*)(ws + 6 * MB);   // 2MB
  u16* Wfc_t   = (u16*)(ws + 8 * MB);   // 8MB
  u16* Wfc2_t  = (u16*)(ws + 16 * MB);  // 8MB
  float* x1    = (float*)(ws + 24 * MB); // 16MB
  u16* h1      = (u16*)(ws + 40 * MB);  // 8MB
  u16* qkv     = (u16*)(ws + 48 * MB);  // 24MB (alive through attn)
  u16* Vt      = (u16*)(ws + 88 * MB);  // 8MB
  u16* yb      = (u16*)(ws + 40 * MB);  // reuse h1 (dead after qkv GEMM)
  u16* h2      = (u16*)(ws + 48 * MB);  // reuse qkv (dead after attn)
  u16* ab      = (u16*)(ws + 56 * MB);  // 32MB (56..88)

  wtrans<<<dim3(3072 / 32, 1024 / 32), 256, 0, stream>>>(W_attn, Wattn_t, 1024, 3072);
  wtrans<<<dim3(1024 / 32, 1024 / 32), 256, 0, stream>>>(W_o, Wo_t, 1024, 1024);
  wtrans<<<dim3(4096 / 32, 1024 / 32), 256, 0, stream>>>(W_fc, Wfc_t, 1024, 4096);
  wtrans<<<dim3(1024 / 32, 4096 / 32), 256, 0, stream>>>(W_fc2, Wfc2_t, 4096, 1024);

  ln_bf16<<<4096, 256, 0, stream>>>(x, ln1_g, ln1_b, h1);
  gemm_bt_p<0, 0><<<dim3(3072 / 128, 4096 / 128), 256, 0, stream>>>(
      h1, Wattn_t, b_attn, nullptr, qkv, 4096, 3072, 1024);
  transpose_v<<<dim3(2048 / 64, 32), 256, 0, stream>>>(qkv, Vt);
  attn_kernel<<<dim3(16, 32), 256, 0, stream>>>(qkv, Vt, yb);
  gemm_bt_n64<2><<<dim3(1024 / 64, 4096 / 128), 256, 0, stream>>>(
      yb, Wo_t, b_o, x, x1, 4096, 1024, 1024);
  ln_bf16<<<4096, 256, 0, stream>>>(x1, ln2_g, ln2_b, h2);
  gemm_bt_p256b<1><<<dim3(4096 / 256, 4096 / 256), 512, 0, stream>>>(
      h2, Wfc_t, b_fc, nullptr, ab, 4096, 4096, 1024);
  gemm_bt_p<2, 1><<<dim3(1024 / 128, 4096 / 128), 256, 0, stream>>>(
      ab, Wfc2_t, b_fc2, x1, out, 4096, 1024, 4096);
}